// Round 10
// baseline (622.356 us; speedup 1.0000x reference)
//
#include <hip/hip_runtime.h>

#define NV 50257
#define NE 512
#define NH 1024
#define NB 1024
#define TSTEPS 10

typedef __bf16 bf16x8 __attribute__((ext_vector_type(8)));
typedef float  f32x4  __attribute__((ext_vector_type(4)));
typedef unsigned short u16;

// fp32 -> bf16 round-to-nearest-even
__device__ __forceinline__ u16 f2bf(float v) {
    unsigned u = __float_as_uint(v);
    unsigned r = u + 0x7fffu + ((u >> 16) & 1u);
    return (u16)(r >> 16);
}

// ---------------------------------------------------------------------------
// streaming fp32 -> bf16 convert (fc_W, W1, W2)
// ---------------------------------------------------------------------------
__global__ void cvt_bf16_kernel(const float* __restrict__ x,
                                u16* __restrict__ y, int n4) {
    int i0 = blockIdx.x * blockDim.x + threadIdx.x;
    int stride = gridDim.x * blockDim.x;
    for (int i = i0; i < n4; i += stride) {
        float4 v = ((const float4*)x)[i];
        ushort4 o;
        o.x = f2bf(v.x); o.y = f2bf(v.y); o.z = f2bf(v.z); o.w = f2bf(v.w);
        ((ushort4*)y)[i] = o;
    }
}

// ---------------------------------------------------------------------------
// embedding gather + dropout mask -> bf16
// ---------------------------------------------------------------------------
__global__ void embed_bf16_kernel(const int* __restrict__ tok,
                                  const float* __restrict__ table,
                                  const float* __restrict__ mask,
                                  u16* __restrict__ ebf) {
    int i = blockIdx.x * blockDim.x + threadIdx.x;   // float4 index
    const int n4 = NB * NE / 4;
    if (i >= n4) return;
    int b = i / (NE / 4);
    int c = i % (NE / 4);
    float4 t = ((const float4*)(table + (size_t)tok[b] * NE))[c];
    float4 m = ((const float4*)mask)[i];
    ushort4 o;
    o.x = f2bf(t.x * m.x); o.y = f2bf(t.y * m.y);
    o.z = f2bf(t.z * m.z); o.w = f2bf(t.w * m.w);
    ((ushort4*)ebf)[i] = o;
}

// ---------------------------------------------------------------------------
// LIF recurrence -> hsum = mask_lif * sum_t spike_t, output bf16
// ---------------------------------------------------------------------------
__global__ void lif_bf16_kernel(const float* __restrict__ delta1,
                                const float* __restrict__ hidden,
                                const float* __restrict__ mask_lif,
                                const float* __restrict__ thr_p,
                                const float* __restrict__ leak_p,
                                u16* __restrict__ hbf) {
    int i = blockIdx.x * blockDim.x + threadIdx.x;
    if (i >= NB * NH / 4) return;
    const float thr = thr_p[0];
    const float leak = leak_p[0];
    float4 d4 = ((const float4*)delta1)[i];
    float4 m4 = ((const float4*)hidden)[i];
    float4 k4 = ((const float4*)mask_lif)[i];
    float dd[4] = {d4.x, d4.y, d4.z, d4.w};
    float mm[4] = {m4.x, m4.y, m4.z, m4.w};
    float kk[4] = {k4.x, k4.y, k4.z, k4.w};
    ushort4 o;
    u16 oo[4];
#pragma unroll
    for (int j = 0; j < 4; ++j) {
        float m = mm[j], cnt = 0.0f;
#pragma unroll
        for (int t = 0; t < TSTEPS; ++t) {
            float mem = leak * m + dd[j];
            float s = ((mem / thr - 1.0f) > 0.0f) ? 1.0f : 0.0f;
            m = mem - thr * s;
            cnt += s;
        }
        oo[j] = f2bf(cnt * kk[j]);
    }
    o.x = oo[0]; o.y = oo[1]; o.z = oo[2]; o.w = oo[3];
    ((ushort4*)hbf)[i] = o;
}

// ---------------------------------------------------------------------------
// bf16 x bf16 MFMA GEMM v3: T3 minimum-2-phase pipeline (guide §5.5 recipe,
// m230-verified 682 TF class), wave-tile 64 x (TBN/2), XCD-grouped 1D grid.
//   C = A*B^T + bias*scale
// Structure per K-step (the one ordering that overlaps without counted waits):
//   stage(t+1)  ->  ds_read+MFMA on buf t  ->  s_waitcnt vmcnt(0); s_barrier
// - stage issued BEFORE compute: HBM/L2 latency hides under ~900 cy of
//   LDS reads + 32 MFMA (round-6's adjacent stage/wait had zero overlap).
// - drain-style vmcnt(0) at END: no counted-tail race class (round-7 bug
//   structurally impossible); raw s_barrier (no compiler vmcnt-drain convoy).
// - WAR: stage(t+1) writes the buffer last read at t-1, separated by the
//   t-1 end barrier (same margin as determinism-proven rounds 8/9).
// - DEPTH=2 -> 48 KB (TBN=256) -> 3 blocks/CU = 12 waves/CU (m114 regime).
// - Fragment-linear LDS (1KB units, lane l -> row l&15, k (l>>4)*8):
//   conflict-free ds_read_b128 (measured SQ_LDS_BANK_CONFLICT = 0).
// - XCD grouping (verified: FETCH 415->99 MB): 1D grid, x=i&7, rb=(i>>3)&7,
//   p=((i>>6)<<3)+x; panels >= P return early. REQUIRES M/TBM == 8.
// Requires K % 32 == 0, K/32 >= 1. N edge clamped (loads) / guarded (stores).
// NOTE: concrete __global__ wrappers (template __global__ fails to link).
// ---------------------------------------------------------------------------
template<int TBM, int TBN, int NWAVE>
__device__ __forceinline__
void gemm_pipe3_body(const u16* __restrict__ Abf, const u16* __restrict__ Bbf,
                     const float* __restrict__ bias, float bias_scale,
                     float* __restrict__ C, u16* __restrict__ Cb,
                     int M, int N, int K) {
    constexpr int AU = TBM / 16;            // A units (1KB each)
    constexpr int BU = TBN / 16;
    constexpr int TOT = AU + BU;
    constexpr int PER = TOT / NWAVE;        // gload_lds per wave per stage
    constexpr int MF = 4;                   // m-frags per wave (64 rows)
    constexpr int NF = TBN / 32;            // n-frags per wave (2 wave-cols)
    static_assert(TOT % NWAVE == 0, "unit split");
    static_assert(NWAVE == 4 && TBM == 128, "wave tiling: 2x2 waves");

    __shared__ u16 sA[2][AU * 512];
    __shared__ u16 sB[2][BU * 512];

    // XCD-grouped decode (requires exactly 8 row-blocks)
    const int i = blockIdx.x;
    const int xcd = i & 7;
    const int rb  = (i >> 3) & 7;
    const int p   = ((i >> 6) << 3) + xcd;
    if (p * TBN >= N) return;               // padded-grid guard (before barriers)
    const int bm = rb * TBM;
    const int bn = p * TBN;

    const int tid = threadIdx.x;
    const int w = tid >> 6;
    const int l = tid & 63;
    const int wr16 = (w >> 1) * MF;         // wave's A unit base
    const int wc16 = (w & 1) * NF;          // wave's B unit base
    const int lrow = l & 15;                // staging row within unit
    const int lk8 = (l >> 4) * 8;           // staging k offset within BK=32
    const int l8 = l * 8;                   // fragment read offset (u16)

    f32x4 acc[MF][NF];
#pragma unroll
    for (int m = 0; m < MF; ++m)
#pragma unroll
        for (int n = 0; n < NF; ++n)
#pragma unroll
            for (int q = 0; q < 4; ++q) acc[m][n][q] = 0.0f;

    const int NT = K / 32;

    auto stage = [&](int buf, int k0) {
#pragma unroll
        for (int s = 0; s < PER; ++s) {
            const int c = w * PER + s;
            if (c < AU) {
                const int row = bm + c * 16 + lrow;
                __builtin_amdgcn_global_load_lds(Abf + (size_t)row * K + k0 + lk8,
                                                 &sA[buf][c * 512], 16, 0, 0);
            } else {
                const int u = c - AU;
                int row = bn + u * 16 + lrow; if (row >= N) row = N - 1;
                __builtin_amdgcn_global_load_lds(Bbf + (size_t)row * K + k0 + lk8,
                                                 &sB[buf][u * 512], 16, 0, 0);
            }
        }
    };

    // prologue: stage tile 0, drain, rendezvous
    stage(0, 0);
    asm volatile("s_waitcnt vmcnt(0)" ::: "memory");
    __builtin_amdgcn_s_barrier();

    int cur = 0;
    for (int t = 0; t < NT; ++t) {
        if (t + 1 < NT) stage(cur ^ 1, (t + 1) * 32);   // issue-early (T3)
        __builtin_amdgcn_sched_barrier(0);

        bf16x8 ah[MF], bh[NF];
#pragma unroll
        for (int m = 0; m < MF; ++m)
            ah[m] = *(const bf16x8*)&sA[cur][(wr16 + m) * 512 + l8];
#pragma unroll
        for (int n = 0; n < NF; ++n)
            bh[n] = *(const bf16x8*)&sB[cur][(wc16 + n) * 512 + l8];

#pragma unroll
        for (int m = 0; m < MF; ++m)
#pragma unroll
            for (int n = 0; n < NF; ++n)
                acc[m][n] = __builtin_amdgcn_mfma_f32_16x16x32_bf16(ah[m], bh[n], acc[m][n], 0, 0, 0);

        __builtin_amdgcn_sched_barrier(0);
        if (t + 1 < NT) {
            asm volatile("s_waitcnt vmcnt(0)" ::: "memory");   // next tile landed
            __builtin_amdgcn_s_barrier();
        }
        cur ^= 1;
    }

    // epilogue: C/D layout col = l&15, row = (l>>4)*4 + reg
    const int lq = (l >> 4) * 4;
    const int wrow = bm + (w >> 1) * 64;
    const int wcol = bn + (w & 1) * (NF * 16);
#pragma unroll
    for (int n = 0; n < NF; ++n) {
        const int gcol = wcol + n * 16 + (l & 15);
        if (gcol >= N) continue;
        const float bb = bias[gcol] * bias_scale;
#pragma unroll
        for (int m = 0; m < MF; ++m) {
            const int grow = wrow + m * 16 + lq;
#pragma unroll
            for (int q = 0; q < 4; ++q) {
                float v = acc[m][n][q] + bb;
                C[(size_t)(grow + q) * N + gcol] = v;
                if (Cb) Cb[(size_t)(grow + q) * N + gcol] = f2bf(v);
            }
        }
    }
}

__global__ __launch_bounds__(256, 3)
void gemm_pipe3_256(const u16* __restrict__ Abf, const u16* __restrict__ Bbf,
                    const float* __restrict__ bias, float bias_scale,
                    float* __restrict__ C, u16* __restrict__ Cb, int M, int N, int K) {
    gemm_pipe3_body<128, 256, 4>(Abf, Bbf, bias, bias_scale, C, Cb, M, N, K);
}

__global__ __launch_bounds__(256, 4)
void gemm_pipe3_128(const u16* __restrict__ Abf, const u16* __restrict__ Bbf,
                    const float* __restrict__ bias, float bias_scale,
                    float* __restrict__ C, u16* __restrict__ Cb, int M, int N, int K) {
    gemm_pipe3_body<128, 128, 4>(Abf, Bbf, bias, bias_scale, C, Cb, M, N, K);
}

// ---------------------------------------------------------------------------
// fp32 fallback kernels (tiny-workspace safety net)
// ---------------------------------------------------------------------------
__global__ void embed_kernel(const int* __restrict__ tok,
                             const float* __restrict__ table,
                             const float* __restrict__ mask,
                             float* __restrict__ emb) {
    int i = blockIdx.x * blockDim.x + threadIdx.x;
    const int n4 = NB * NE / 4;
    if (i >= n4) return;
    int b = i / (NE / 4);
    int c = i % (NE / 4);
    float4 t = ((const float4*)(table + (size_t)tok[b] * NE))[c];
    float4 m = ((const float4*)mask)[i];
    float4 o;
    o.x = t.x * m.x; o.y = t.y * m.y; o.z = t.z * m.z; o.w = t.w * m.w;
    ((float4*)emb)[i] = o;
}

__global__ void lif_kernel(const float* __restrict__ delta1,
                           const float* __restrict__ hidden,
                           const float* __restrict__ mask_lif,
                           const float* __restrict__ thr_p,
                           const float* __restrict__ leak_p,
                           float* __restrict__ hsum) {
    int i = blockIdx.x * blockDim.x + threadIdx.x;
    if (i >= NB * NH) return;
    const float thr = thr_p[0];
    const float leak = leak_p[0];
    float d = delta1[i];
    float m = hidden[i];
    float cnt = 0.0f;
#pragma unroll
    for (int t = 0; t < TSTEPS; ++t) {
        float mem = leak * m + d;
        float s = ((mem / thr - 1.0f) > 0.0f) ? 1.0f : 0.0f;
        m = mem - thr * s;
        cnt += s;
    }
    hsum[i] = cnt * mask_lif[i];
}

#define BM 128
#define BN 128
#define BK 16

__global__ __launch_bounds__(256)
void gemm_nt(const float* __restrict__ A, const float* __restrict__ Bm,
             const float* __restrict__ bias, float bias_scale,
             float* __restrict__ C, int M, int N, int K) {
    __shared__ float As[BK][BM + 4];
    __shared__ float Bs[BK][BN + 4];

    const int tid = threadIdx.x;
    const int bm = blockIdx.y * BM;
    const int bn = blockIdx.x * BN;
    const int tx = tid & 15;
    const int ty = tid >> 4;
    const int tm = ty * 8;
    const int tn0 = tx * 4;
    const int tn1 = 64 + tx * 4;

    float acc[8][8];
#pragma unroll
    for (int i = 0; i < 8; ++i)
#pragma unroll
        for (int j = 0; j < 8; ++j) acc[i][j] = 0.0f;

    constexpr int LDA4 = BK / 4;

    for (int k0 = 0; k0 < K; k0 += BK) {
#pragma unroll
        for (int idx = tid; idx < BM * LDA4; idx += 256) {
            int m = idx / LDA4, c = idx % LDA4;
            float4 v = *(const float4*)(A + (size_t)(bm + m) * K + k0 + c * 4);
            As[c * 4 + 0][m] = v.x;
            As[c * 4 + 1][m] = v.y;
            As[c * 4 + 2][m] = v.z;
            As[c * 4 + 3][m] = v.w;
        }
#pragma unroll
        for (int idx = tid; idx < BN * LDA4; idx += 256) {
            int n = idx / LDA4, c = idx % LDA4;
            float4 v = make_float4(0.f, 0.f, 0.f, 0.f);
            int gn = bn + n;
            if (gn < N) v = *(const float4*)(Bm + (size_t)gn * K + k0 + c * 4);
            Bs[c * 4 + 0][n] = v.x;
            Bs[c * 4 + 1][n] = v.y;
            Bs[c * 4 + 2][n] = v.z;
            Bs[c * 4 + 3][n] = v.w;
        }
        __syncthreads();

#pragma unroll
        for (int k = 0; k < BK; ++k) {
            float4 a0 = *(const float4*)&As[k][tm];
            float4 a1 = *(const float4*)&As[k][tm + 4];
            float4 b0 = *(const float4*)&Bs[k][tn0];
            float4 b1 = *(const float4*)&Bs[k][tn1];
            float a[8] = {a0.x, a0.y, a0.z, a0.w, a1.x, a1.y, a1.z, a1.w};
            float bb[8] = {b0.x, b0.y, b0.z, b0.w, b1.x, b1.y, b1.z, b1.w};
#pragma unroll
            for (int i = 0; i < 8; ++i)
#pragma unroll
                for (int j = 0; j < 8; ++j)
                    acc[i][j] = fmaf(a[i], bb[j], acc[i][j]);
        }
        __syncthreads();
    }

#pragma unroll
    for (int i = 0; i < 8; ++i) {
        size_t row = (size_t)(bm + tm + i) * N;
#pragma unroll
        for (int j = 0; j < 8; ++j) {
            int gn = bn + ((j < 4) ? (tn0 + j) : (tn1 + j - 4));
            if (gn < N)
                C[row + gn] = acc[i][j] + bias[gn] * bias_scale;
        }
    }
}

// ---------------------------------------------------------------------------
static inline int grid1d(int N, int TBN) {
    int P = (N + TBN - 1) / TBN;
    int P8 = ((P + 7) / 8) * 8;
    return 8 * P8;                  // 8 row-blocks x padded panels
}

extern "C" void kernel_launch(void* const* d_in, const int* in_sizes, int n_in,
                              void* d_out, int out_size, void* d_ws, size_t ws_size,
                              hipStream_t stream) {
    const int*   tok      = (const int*)  d_in[0];
    const float* hidden   = (const float*)d_in[1];
    const float* table    = (const float*)d_in[2];
    const float* W1       = (const float*)d_in[3];
    const float* b1       = (const float*)d_in[4];
    const float* W2       = (const float*)d_in[5];
    const float* b2       = (const float*)d_in[6];
    const float* fc_W     = (const float*)d_in[7];
    const float* fc_b     = (const float*)d_in[8];
    const float* thr      = (const float*)d_in[9];
    const float* leak     = (const float*)d_in[10];
    const float* mask_emb = (const float*)d_in[11];
    const float* mask_lif = (const float*)d_in[12];

    float* linear = (float*)d_out;                   // [B,V]
    float* outbuf = (float*)d_out + (size_t)NB * NV; // [B,H]

    const size_t SZ_EB  = (size_t)NB * NE * 2;   // ebf
    const size_t SZ_D1  = (size_t)NB * NH * 4;   // delta1 fp32
    const size_t SZ_HB  = (size_t)NB * NH * 2;   // hbf
    const size_t SZ_OB  = (size_t)NB * NH * 2;   // obf
    const size_t SZ_W1B = (size_t)NH * NE * 2;   // W1 bf16
    const size_t SZ_W2B = (size_t)NH * NH * 2;   // W2 bf16
    const size_t SZ_WB  = (size_t)NV * NH * 2;   // fc_W bf16 (~103 MB)
    const size_t need_bf = SZ_EB + SZ_D1 + SZ_HB + SZ_OB + SZ_W1B + SZ_W2B + SZ_WB;

    char* p = (char*)d_ws;

    if (ws_size >= need_bf) {
        u16*   ebf    = (u16*)p;   p += SZ_EB;
        float* delta1 = (float*)p; p += SZ_D1;
        u16*   hbf    = (u16*)p;   p += SZ_HB;
        u16*   obf    = (u16*)p;   p += SZ_OB;
        u16*   w1b    = (u16*)p;   p += SZ_W1B;
        u16*   w2b    = (u16*)p;   p += SZ_W2B;
        u16*   fcwb   = (u16*)p;   p += SZ_WB;

        // weight converts (fc_W dominates: ~310 MB traffic, HBM-bound)
        cvt_bf16_kernel<<<2048, 256, 0, stream>>>(fc_W, fcwb, NV * NH / 4);
        cvt_bf16_kernel<<<512, 256, 0, stream>>>(W1, w1b, NH * NE / 4);
        cvt_bf16_kernel<<<512, 256, 0, stream>>>(W2, w2b, NH * NH / 4);
        // 0: embedding gather + mask -> bf16
        {
            int n4 = NB * NE / 4;
            embed_bf16_kernel<<<(n4 + 255) / 256, 256, 0, stream>>>(tok, table, mask_emb, ebf);
        }
        // 1: delta1 = ebf @ w1b^T + b1   (M=B, N=H, K=E)
        gemm_pipe3_128<<<grid1d(NH, 128), 256, 0, stream>>>(ebf, w1b, b1, 1.0f,
                                                            delta1, (u16*)nullptr, NB, NH, NE);
        // 2: LIF -> hbf (bf16)
        {
            int n = NB * NH / 4;
            lif_bf16_kernel<<<(n + 255) / 256, 256, 0, stream>>>(delta1, hidden, mask_lif,
                                                                 thr, leak, hbf);
        }
        // 3: out = hbf @ w2b^T + 10*b2 -> outbuf (fp32) + obf (bf16)
        gemm_pipe3_128<<<grid1d(NH, 128), 256, 0, stream>>>(hbf, w2b, b2, (float)TSTEPS,
                                                            outbuf, obf, NB, NH, NH);
        // 4: linear = obf @ fcwb^T + fc_b  (M=B, N=V, K=H)
        gemm_pipe3_256<<<grid1d(NV, 256), 256, 0, stream>>>(obf, fcwb, fc_b, 1.0f,
                                                            linear, (u16*)nullptr, NB, NV, NH);
    } else {
        // ----- pure fp32 fallback -----
        float* emb    = (float*)p;  p += (size_t)NB * NE * 4;
        float* delta1 = (float*)p;  p += SZ_D1;
        float* hsum   = (float*)p;

        int n4 = NB * NE / 4;
        embed_kernel<<<(n4 + 255) / 256, 256, 0, stream>>>(tok, table, mask_emb, emb);
        {
            dim3 grid(NH / BN, NB / BM);
            gemm_nt<<<grid, 256, 0, stream>>>(emb, W1, b1, 1.0f, delta1, NB, NH, NE);
        }
        {
            int n = NB * NH;
            lif_kernel<<<(n + 255) / 256, 256, 0, stream>>>(delta1, hidden, mask_lif,
                                                            thr, leak, hsum);
        }
        {
            dim3 grid(NH / BN, NB / BM);
            gemm_nt<<<grid, 256, 0, stream>>>(hsum, W2, b2, (float)TSTEPS, outbuf, NB, NH, NH);
        }
        {
            dim3 grid((NV + BN - 1) / BN, NB / BM);
            gemm_nt<<<grid, 256, 0, stream>>>(outbuf, fc_W, fc_b, 1.0f, linear, NB, NV, NH);
        }
    }
}

// Round 11
// 137.598 us; speedup vs baseline: 4.5230x; 4.5230x over previous
//
#include <hip/hip_runtime.h>

#define NV 50257
#define NE 512
#define NH 1024
#define NB 1024
#define TSTEPS 10

typedef __bf16 bf16x8 __attribute__((ext_vector_type(8)));
typedef float  f32x4  __attribute__((ext_vector_type(4)));
typedef unsigned short u16;

// fp32 -> bf16 round-to-nearest-even
__device__ __forceinline__ u16 f2bf(float v) {
    unsigned u = __float_as_uint(v);
    unsigned r = u + 0x7fffu + ((u >> 16) & 1u);
    return (u16)(r >> 16);
}

// ---------------------------------------------------------------------------
// flag init (d_ws is poisoned once, not re-poisoned between replays)
// ---------------------------------------------------------------------------
__global__ void init_flag_kernel(unsigned* flag) { *flag = 0u; }

// ---------------------------------------------------------------------------
// streaming fp32 -> bf16 convert (W1, W2 unconditional; fc_W conditional)
// ---------------------------------------------------------------------------
__global__ void cvt_bf16_kernel(const float* __restrict__ x,
                                u16* __restrict__ y, int n4) {
    int i0 = blockIdx.x * blockDim.x + threadIdx.x;
    int stride = gridDim.x * blockDim.x;
    for (int i = i0; i < n4; i += stride) {
        float4 v = ((const float4*)x)[i];
        ushort4 o;
        o.x = f2bf(v.x); o.y = f2bf(v.y); o.z = f2bf(v.z); o.w = f2bf(v.w);
        ((ushort4*)y)[i] = o;
    }
}

__global__ void cvt_bf16_cond_kernel(const unsigned* __restrict__ flag,
                                     const float* __restrict__ x,
                                     u16* __restrict__ y, int n4) {
    if (*flag == 0u) return;            // spikes never fired: fcwb unused
    int i0 = blockIdx.x * blockDim.x + threadIdx.x;
    int stride = gridDim.x * blockDim.x;
    for (int i = i0; i < n4; i += stride) {
        float4 v = ((const float4*)x)[i];
        ushort4 o;
        o.x = f2bf(v.x); o.y = f2bf(v.y); o.z = f2bf(v.z); o.w = f2bf(v.w);
        ((ushort4*)y)[i] = o;
    }
}

// ---------------------------------------------------------------------------
// embedding gather + dropout mask -> bf16
// ---------------------------------------------------------------------------
__global__ void embed_bf16_kernel(const int* __restrict__ tok,
                                  const float* __restrict__ table,
                                  const float* __restrict__ mask,
                                  u16* __restrict__ ebf) {
    int i = blockIdx.x * blockDim.x + threadIdx.x;   // float4 index
    const int n4 = NB * NE / 4;
    if (i >= n4) return;
    int b = i / (NE / 4);
    int c = i % (NE / 4);
    float4 t = ((const float4*)(table + (size_t)tok[b] * NE))[c];
    float4 m = ((const float4*)mask)[i];
    ushort4 o;
    o.x = f2bf(t.x * m.x); o.y = f2bf(t.y * m.y);
    o.z = f2bf(t.z * m.z); o.w = f2bf(t.w * m.w);
    ((ushort4*)ebf)[i] = o;
}

// ---------------------------------------------------------------------------
// LIF recurrence -> hsum = mask_lif * sum_t spike_t (bf16) + spike flag.
// SNN spike-sparsity detection: if NO element of hsum is nonzero, the rest
// of the network collapses (out = 10*b2 broadcast, linear = fc_b + 10*b2@W).
// ---------------------------------------------------------------------------
__global__ void lif_bf16_flag_kernel(const float* __restrict__ delta1,
                                     const float* __restrict__ hidden,
                                     const float* __restrict__ mask_lif,
                                     const float* __restrict__ thr_p,
                                     const float* __restrict__ leak_p,
                                     u16* __restrict__ hbf,
                                     unsigned* __restrict__ flag) {
    int i = blockIdx.x * blockDim.x + threadIdx.x;
    if (i >= NB * NH / 4) return;
    const float thr = thr_p[0];
    const float leak = leak_p[0];
    float4 d4 = ((const float4*)delta1)[i];
    float4 m4 = ((const float4*)hidden)[i];
    float4 k4 = ((const float4*)mask_lif)[i];
    float dd[4] = {d4.x, d4.y, d4.z, d4.w};
    float mm[4] = {m4.x, m4.y, m4.z, m4.w};
    float kk[4] = {k4.x, k4.y, k4.z, k4.w};
    ushort4 o;
    u16 oo[4];
    bool nz = false;
#pragma unroll
    for (int j = 0; j < 4; ++j) {
        float m = mm[j], cnt = 0.0f;
#pragma unroll
        for (int t = 0; t < TSTEPS; ++t) {
            float mem = leak * m + dd[j];
            float s = ((mem / thr - 1.0f) > 0.0f) ? 1.0f : 0.0f;
            m = mem - thr * s;
            cnt += s;
        }
        float v = cnt * kk[j];
        nz |= (v != 0.0f);
        oo[j] = f2bf(v);
    }
    o.x = oo[0]; o.y = oo[1]; o.z = oo[2]; o.w = oo[3];
    ((ushort4*)hbf)[i] = o;
    if (nz) atomicOr(flag, 1u);          // device-scope; wave-coalesced (G12)
}

// ---------------------------------------------------------------------------
// zero-spike fast path kernels (run iff flag == 0)
// ---------------------------------------------------------------------------
// out = 10*b2 broadcast over rows (fp32 second output + bf16 mirror)
__global__ void bcast_out_kernel(const unsigned* __restrict__ flag,
                                 const float* __restrict__ b2,
                                 float* __restrict__ outbuf,
                                 u16* __restrict__ obf) {
    if (*flag != 0u) return;
    int i0 = blockIdx.x * blockDim.x + threadIdx.x;
    int stride = gridDim.x * blockDim.x;
    const int n4 = NB * NH / 4;
    for (int i = i0; i < n4; i += stride) {
        int h4 = i & (NH / 4 - 1);
        float4 v = ((const float4*)b2)[h4];
        v.x *= (float)TSTEPS; v.y *= (float)TSTEPS;
        v.z *= (float)TSTEPS; v.w *= (float)TSTEPS;
        ((float4*)outbuf)[i] = v;
        ushort4 ob;
        ob.x = f2bf(v.x); ob.y = f2bf(v.y); ob.z = f2bf(v.z); ob.w = f2bf(v.w);
        ((ushort4*)obf)[i] = ob;
    }
}

// y[v] = fc_b[v] + 10 * dot(b2, fc_W[v,:])  — one wave per column,
// lanes read 64 consecutive float4 = 1KB contiguous per instruction.
__global__ void matvec_fc_kernel(const unsigned* __restrict__ flag,
                                 const float* __restrict__ b2,
                                 const float* __restrict__ fcW,
                                 const float* __restrict__ fc_b,
                                 float* __restrict__ y) {
    if (*flag != 0u) return;
    const int col = blockIdx.x * 4 + (threadIdx.x >> 6);
    const int l = threadIdx.x & 63;
    if (col >= NV) return;
    const float4* row = (const float4*)(fcW + (size_t)col * NH);
    const float4* bb = (const float4*)b2;
    float s = 0.0f;
#pragma unroll
    for (int it = 0; it < NH / 256; ++it) {      // 4 iters of 64 float4
        float4 v = row[it * 64 + l];
        float4 b = bb[it * 64 + l];
        s += v.x * b.x + v.y * b.y + v.z * b.z + v.w * b.w;
    }
#pragma unroll
    for (int off = 32; off > 0; off >>= 1) s += __shfl_down(s, off);
    if (l == 0) y[col] = fc_b[col] + (float)TSTEPS * s;
}

// linear[b, v] = y[v] broadcast over all rows (coalesced row-major writes)
__global__ void bcast_linear_kernel(const unsigned* __restrict__ flag,
                                    const float* __restrict__ y,
                                    float* __restrict__ linear) {
    if (*flag != 0u) return;
    const int c0 = blockIdx.x * 1024;            // column chunk
    const int r0 = blockIdx.y * 4;               // 4 rows per block
    const int t = threadIdx.x;
    float vy[4];
#pragma unroll
    for (int k = 0; k < 4; ++k) {
        int c = c0 + t + k * 256;
        vy[k] = (c < NV) ? y[c] : 0.0f;
    }
#pragma unroll
    for (int r = 0; r < 4; ++r) {
        float* dst = linear + (size_t)(r0 + r) * NV;
#pragma unroll
        for (int k = 0; k < 4; ++k) {
            int c = c0 + t + k * 256;
            if (c < NV) dst[c] = vy[k];
        }
    }
}

// ---------------------------------------------------------------------------
// bf16 x bf16 MFMA GEMM (round-9 pipeline, best measured: counted vmcnt,
// DEPTH=3, wave-tile 64 x (TBN/2), XCD-grouped 1D grid). C = A*B^T + bias*s.
// - Fragment-linear LDS (1KB units, lane l -> row l&15, k (l>>4)*8):
//   conflict-free ds_read_b128 (measured SQ_LDS_BANK_CONFLICT = 0).
// - vmcnt(PER) steady / vmcnt(0) last iter (round-7 tail race fixed),
//   one s_barrier per step, stage(t+2) -> buffer last read at t-1.
// - XCD grouping (verified: FETCH 415->99 MB). REQUIRES M/TBM == 8.
// NOTE: concrete __global__ wrappers (template __global__ fails to link).
// ---------------------------------------------------------------------------
template<int TBM, int TBN, int NWAVE>
__device__ __forceinline__
void gemm_pipe2_body(const u16* __restrict__ Abf, const u16* __restrict__ Bbf,
                     const float* __restrict__ bias, float bias_scale,
                     float* __restrict__ C, u16* __restrict__ Cb,
                     int M, int N, int K) {
    constexpr int AU = TBM / 16;
    constexpr int BU = TBN / 16;
    constexpr int TOT = AU + BU;
    constexpr int PER = TOT / NWAVE;
    constexpr int MF = 4;
    constexpr int NF = TBN / 32;
    constexpr int DEPTH = 3;
    static_assert(TOT % NWAVE == 0, "unit split");
    static_assert(NWAVE == 4 && TBM == 128, "wave tiling: 2x2 waves");

    __shared__ u16 sA[DEPTH][AU * 512];
    __shared__ u16 sB[DEPTH][BU * 512];

    const int i = blockIdx.x;
    const int xcd = i & 7;
    const int rb  = (i >> 3) & 7;
    const int p   = ((i >> 6) << 3) + xcd;
    if (p * TBN >= N) return;               // padded-grid guard (before barriers)
    const int bm = rb * TBM;
    const int bn = p * TBN;

    const int tid = threadIdx.x;
    const int w = tid >> 6;
    const int l = tid & 63;
    const int wr16 = (w >> 1) * MF;
    const int wc16 = (w & 1) * NF;
    const int lrow = l & 15;
    const int lk8 = (l >> 4) * 8;
    const int l8 = l * 8;

    f32x4 acc[MF][NF];
#pragma unroll
    for (int m = 0; m < MF; ++m)
#pragma unroll
        for (int n = 0; n < NF; ++n)
#pragma unroll
            for (int q = 0; q < 4; ++q) acc[m][n][q] = 0.0f;

    const int NT = K / 32;

    auto stage = [&](int buf, int k0) {
#pragma unroll
        for (int s = 0; s < PER; ++s) {
            const int c = w * PER + s;
            if (c < AU) {
                const int row = bm + c * 16 + lrow;
                __builtin_amdgcn_global_load_lds(Abf + (size_t)row * K + k0 + lk8,
                                                 &sA[buf][c * 512], 16, 0, 0);
            } else {
                const int u = c - AU;
                int row = bn + u * 16 + lrow; if (row >= N) row = N - 1;
                __builtin_amdgcn_global_load_lds(Bbf + (size_t)row * K + k0 + lk8,
                                                 &sB[buf][u * 512], 16, 0, 0);
            }
        }
    };

    stage(0, 0);
    stage(1, 32);

    int cur = 0;
    for (int t = 0; t < NT; ++t) {
        if (t + 1 < NT) {
            asm volatile("s_waitcnt vmcnt(%0)" :: "n"(PER) : "memory");
        } else {
            asm volatile("s_waitcnt vmcnt(0)" ::: "memory");
        }
        __builtin_amdgcn_sched_barrier(0);
        __builtin_amdgcn_s_barrier();
        __builtin_amdgcn_sched_barrier(0);

        if (t + 2 < NT) {
            int nb = cur + 2; if (nb >= DEPTH) nb -= DEPTH;
            stage(nb, (t + 2) * 32);
        }

        bf16x8 ah[MF], bh[NF];
#pragma unroll
        for (int m = 0; m < MF; ++m)
            ah[m] = *(const bf16x8*)&sA[cur][(wr16 + m) * 512 + l8];
#pragma unroll
        for (int n = 0; n < NF; ++n)
            bh[n] = *(const bf16x8*)&sB[cur][(wc16 + n) * 512 + l8];

#pragma unroll
        for (int m = 0; m < MF; ++m)
#pragma unroll
            for (int n = 0; n < NF; ++n)
                acc[m][n] = __builtin_amdgcn_mfma_f32_16x16x32_bf16(ah[m], bh[n], acc[m][n], 0, 0, 0);

        __builtin_amdgcn_sched_barrier(0);
        cur = (cur + 1 == DEPTH) ? 0 : cur + 1;
    }

    const int lq = (l >> 4) * 4;
    const int wrow = bm + (w >> 1) * 64;
    const int wcol = bn + (w & 1) * (NF * 16);
#pragma unroll
    for (int n = 0; n < NF; ++n) {
        const int gcol = wcol + n * 16 + (l & 15);
        if (gcol >= N) continue;
        const float bb = bias[gcol] * bias_scale;
#pragma unroll
        for (int m = 0; m < MF; ++m) {
            const int grow = wrow + m * 16 + lq;
#pragma unroll
            for (int q = 0; q < 4; ++q) {
                float v = acc[m][n][q] + bb;
                C[(size_t)(grow + q) * N + gcol] = v;
                if (Cb) Cb[(size_t)(grow + q) * N + gcol] = f2bf(v);
            }
        }
    }
}

// unconditional (kernel 1)
__global__ __launch_bounds__(256)
void gemm_pipe2_128(const u16* __restrict__ Abf, const u16* __restrict__ Bbf,
                    const float* __restrict__ bias, float bias_scale,
                    float* __restrict__ C, u16* __restrict__ Cb, int M, int N, int K) {
    gemm_pipe2_body<128, 128, 4>(Abf, Bbf, bias, bias_scale, C, Cb, M, N, K);
}

// conditional: run only when spikes fired (flag != 0)
__global__ __launch_bounds__(256)
void gemm_pipe2_128_cond(const unsigned* __restrict__ flag,
                         const u16* __restrict__ Abf, const u16* __restrict__ Bbf,
                         const float* __restrict__ bias, float bias_scale,
                         float* __restrict__ C, u16* __restrict__ Cb, int M, int N, int K) {
    if (*flag == 0u) return;
    gemm_pipe2_body<128, 128, 4>(Abf, Bbf, bias, bias_scale, C, Cb, M, N, K);
}

__global__ __launch_bounds__(256, 2)
void gemm_pipe2_256_cond(const unsigned* __restrict__ flag,
                         const u16* __restrict__ Abf, const u16* __restrict__ Bbf,
                         const float* __restrict__ bias, float bias_scale,
                         float* __restrict__ C, u16* __restrict__ Cb, int M, int N, int K) {
    if (*flag == 0u) return;
    gemm_pipe2_body<128, 256, 4>(Abf, Bbf, bias, bias_scale, C, Cb, M, N, K);
}

// ---------------------------------------------------------------------------
// fp32 fallback kernels (tiny-workspace safety net)
// ---------------------------------------------------------------------------
__global__ void embed_kernel(const int* __restrict__ tok,
                             const float* __restrict__ table,
                             const float* __restrict__ mask,
                             float* __restrict__ emb) {
    int i = blockIdx.x * blockDim.x + threadIdx.x;
    const int n4 = NB * NE / 4;
    if (i >= n4) return;
    int b = i / (NE / 4);
    int c = i % (NE / 4);
    float4 t = ((const float4*)(table + (size_t)tok[b] * NE))[c];
    float4 m = ((const float4*)mask)[i];
    float4 o;
    o.x = t.x * m.x; o.y = t.y * m.y; o.z = t.z * m.z; o.w = t.w * m.w;
    ((float4*)emb)[i] = o;
}

__global__ void lif_kernel(const float* __restrict__ delta1,
                           const float* __restrict__ hidden,
                           const float* __restrict__ mask_lif,
                           const float* __restrict__ thr_p,
                           const float* __restrict__ leak_p,
                           float* __restrict__ hsum) {
    int i = blockIdx.x * blockDim.x + threadIdx.x;
    if (i >= NB * NH) return;
    const float thr = thr_p[0];
    const float leak = leak_p[0];
    float d = delta1[i];
    float m = hidden[i];
    float cnt = 0.0f;
#pragma unroll
    for (int t = 0; t < TSTEPS; ++t) {
        float mem = leak * m + d;
        float s = ((mem / thr - 1.0f) > 0.0f) ? 1.0f : 0.0f;
        m = mem - thr * s;
        cnt += s;
    }
    hsum[i] = cnt * mask_lif[i];
}

#define BM 128
#define BN 128
#define BK 16

__global__ __launch_bounds__(256)
void gemm_nt(const float* __restrict__ A, const float* __restrict__ Bm,
             const float* __restrict__ bias, float bias_scale,
             float* __restrict__ C, int M, int N, int K) {
    __shared__ float As[BK][BM + 4];
    __shared__ float Bs[BK][BN + 4];

    const int tid = threadIdx.x;
    const int bm = blockIdx.y * BM;
    const int bn = blockIdx.x * BN;
    const int tx = tid & 15;
    const int ty = tid >> 4;
    const int tm = ty * 8;
    const int tn0 = tx * 4;
    const int tn1 = 64 + tx * 4;

    float acc[8][8];
#pragma unroll
    for (int i = 0; i < 8; ++i)
#pragma unroll
        for (int j = 0; j < 8; ++j) acc[i][j] = 0.0f;

    constexpr int LDA4 = BK / 4;

    for (int k0 = 0; k0 < K; k0 += BK) {
#pragma unroll
        for (int idx = tid; idx < BM * LDA4; idx += 256) {
            int m = idx / LDA4, c = idx % LDA4;
            float4 v = *(const float4*)(A + (size_t)(bm + m) * K + k0 + c * 4);
            As[c * 4 + 0][m] = v.x;
            As[c * 4 + 1][m] = v.y;
            As[c * 4 + 2][m] = v.z;
            As[c * 4 + 3][m] = v.w;
        }
#pragma unroll
        for (int idx = tid; idx < BN * LDA4; idx += 256) {
            int n = idx / LDA4, c = idx % LDA4;
            float4 v = make_float4(0.f, 0.f, 0.f, 0.f);
            int gn = bn + n;
            if (gn < N) v = *(const float4*)(Bm + (size_t)gn * K + k0 + c * 4);
            Bs[c * 4 + 0][n] = v.x;
            Bs[c * 4 + 1][n] = v.y;
            Bs[c * 4 + 2][n] = v.z;
            Bs[c * 4 + 3][n] = v.w;
        }
        __syncthreads();

#pragma unroll
        for (int k = 0; k < BK; ++k) {
            float4 a0 = *(const float4*)&As[k][tm];
            float4 a1 = *(const float4*)&As[k][tm + 4];
            float4 b0 = *(const float4*)&Bs[k][tn0];
            float4 b1 = *(const float4*)&Bs[k][tn1];
            float a[8] = {a0.x, a0.y, a0.z, a0.w, a1.x, a1.y, a1.z, a1.w};
            float bb[8] = {b0.x, b0.y, b0.z, b0.w, b1.x, b1.y, b1.z, b1.w};
#pragma unroll
            for (int i = 0; i < 8; ++i)
#pragma unroll
                for (int j = 0; j < 8; ++j)
                    acc[i][j] = fmaf(a[i], bb[j], acc[i][j]);
        }
        __syncthreads();
    }

#pragma unroll
    for (int i = 0; i < 8; ++i) {
        size_t row = (size_t)(bm + tm + i) * N;
#pragma unroll
        for (int j = 0; j < 8; ++j) {
            int gn = bn + ((j < 4) ? (tn0 + j) : (tn1 + j - 4));
            if (gn < N)
                C[row + gn] = acc[i][j] + bias[gn] * bias_scale;
        }
    }
}

// ---------------------------------------------------------------------------
static inline int grid1d(int N, int TBN) {
    int P = (N + TBN - 1) / TBN;
    int P8 = ((P + 7) / 8) * 8;
    return 8 * P8;                  // 8 row-blocks x padded panels
}

extern "C" void kernel_launch(void* const* d_in, const int* in_sizes, int n_in,
                              void* d_out, int out_size, void* d_ws, size_t ws_size,
                              hipStream_t stream) {
    const int*   tok      = (const int*)  d_in[0];
    const float* hidden   = (const float*)d_in[1];
    const float* table    = (const float*)d_in[2];
    const float* W1       = (const float*)d_in[3];
    const float* b1       = (const float*)d_in[4];
    const float* W2       = (const float*)d_in[5];
    const float* b2       = (const float*)d_in[6];
    const float* fc_W     = (const float*)d_in[7];
    const float* fc_b     = (const float*)d_in[8];
    const float* thr      = (const float*)d_in[9];
    const float* leak     = (const float*)d_in[10];
    const float* mask_emb = (const float*)d_in[11];
    const float* mask_lif = (const float*)d_in[12];

    float* linear = (float*)d_out;                   // [B,V]
    float* outbuf = (float*)d_out + (size_t)NB * NV; // [B,H]

    const size_t SZ_FLAG = 16;                   // flag (16B aligned)
    const size_t SZ_Y   = ((size_t)NV * 4 + 15) / 16 * 16;  // y[V]
    const size_t SZ_EB  = (size_t)NB * NE * 2;   // ebf
    const size_t SZ_D1  = (size_t)NB * NH * 4;   // delta1 fp32
    const size_t SZ_HB  = (size_t)NB * NH * 2;   // hbf
    const size_t SZ_OB  = (size_t)NB * NH * 2;   // obf
    const size_t SZ_W1B = (size_t)NH * NE * 2;   // W1 bf16
    const size_t SZ_W2B = (size_t)NH * NH * 2;   // W2 bf16
    const size_t SZ_WB  = (size_t)NV * NH * 2;   // fc_W bf16 (~103 MB)
    const size_t need_bf = SZ_FLAG + SZ_Y + SZ_EB + SZ_D1 + SZ_HB + SZ_OB
                         + SZ_W1B + SZ_W2B + SZ_WB;

    char* p = (char*)d_ws;

    if (ws_size >= need_bf) {
        unsigned* flag = (unsigned*)p; p += SZ_FLAG;
        float* y      = (float*)p;     p += SZ_Y;
        u16*   ebf    = (u16*)p;       p += SZ_EB;
        float* delta1 = (float*)p;     p += SZ_D1;
        u16*   hbf    = (u16*)p;       p += SZ_HB;
        u16*   obf    = (u16*)p;       p += SZ_OB;
        u16*   w1b    = (u16*)p;       p += SZ_W1B;
        u16*   w2b    = (u16*)p;       p += SZ_W2B;
        u16*   fcwb   = (u16*)p;       p += SZ_WB;

        // flag = 0
        init_flag_kernel<<<1, 1, 0, stream>>>(flag);
        // small weight converts (always needed)
        cvt_bf16_kernel<<<512, 256, 0, stream>>>(W1, w1b, NH * NE / 4);
        cvt_bf16_kernel<<<512, 256, 0, stream>>>(W2, w2b, NH * NH / 4);
        // 0: embedding gather + mask -> bf16
        {
            int n4 = NB * NE / 4;
            embed_bf16_kernel<<<(n4 + 255) / 256, 256, 0, stream>>>(tok, table, mask_emb, ebf);
        }
        // 1: delta1 = ebf @ w1b^T + b1   (M=B, N=H, K=E) — always
        gemm_pipe2_128<<<grid1d(NH, 128), 256, 0, stream>>>(ebf, w1b, b1, 1.0f,
                                                            delta1, (u16*)nullptr, NB, NH, NE);
        // 2: LIF -> hbf (bf16) + spike flag
        {
            int n = NB * NH / 4;
            lif_bf16_flag_kernel<<<(n + 255) / 256, 256, 0, stream>>>(delta1, hidden, mask_lif,
                                                                      thr, leak, hbf, flag);
        }
        // ---- spike path (flag != 0): full MFMA decode ----
        cvt_bf16_cond_kernel<<<2048, 256, 0, stream>>>(flag, fc_W, fcwb, NV * NH / 4);
        gemm_pipe2_128_cond<<<grid1d(NH, 128), 256, 0, stream>>>(flag, hbf, w2b, b2, (float)TSTEPS,
                                                                 outbuf, obf, NB, NH, NH);
        gemm_pipe2_256_cond<<<grid1d(NV, 256), 256, 0, stream>>>(flag, obf, fcwb, fc_b, 1.0f,
                                                                 linear, (u16*)nullptr, NB, NV, NH);
        // ---- zero-spike fast path (flag == 0): hsum==0 => out = 10*b2
        //      broadcast, linear = fc_b + 10*(b2 @ fc_W^T) broadcast ----
        bcast_out_kernel<<<1024, 256, 0, stream>>>(flag, b2, outbuf, obf);
        matvec_fc_kernel<<<(NV + 3) / 4, 256, 0, stream>>>(flag, b2, fc_W, fc_b, y);
        {
            dim3 grid((NV + 1023) / 1024, NB / 4);
            bcast_linear_kernel<<<grid, 256, 0, stream>>>(flag, y, linear);
        }
    } else {
        // ----- pure fp32 fallback -----
        float* emb    = (float*)p;  p += (size_t)NB * NE * 4;
        float* delta1 = (float*)p;  p += SZ_D1;
        float* hsum   = (float*)p;

        int n4 = NB * NE / 4;
        embed_kernel<<<(n4 + 255) / 256, 256, 0, stream>>>(tok, table, mask_emb, emb);
        {
            dim3 grid(NH / BN, NB / BM);
            gemm_nt<<<grid, 256, 0, stream>>>(emb, W1, b1, 1.0f, delta1, NB, NH, NE);
        }
        {
            int n = NB * NH;
            lif_kernel<<<(n + 255) / 256, 256, 0, stream>>>(delta1, hidden, mask_lif,
                                                            thr, leak, hsum);
        }
        {
            dim3 grid(NH / BN, NB / BM);
            gemm_nt<<<grid, 256, 0, stream>>>(hsum, W2, b2, (float)TSTEPS, outbuf, NB, NH, NH);
        }
        {
            dim3 grid((NV + BN - 1) / BN, NB / BM);
            gemm_nt<<<grid, 256, 0, stream>>>(outbuf, fc_W, fc_b, 1.0f, linear, NB, NV, NH);
        }
    }
}

// Round 12
// 82.248 us; speedup vs baseline: 7.5669x; 1.6730x over previous
//
#include <hip/hip_runtime.h>

#define NV 50257
#define NE 512
#define NH 1024
#define NB 1024
#define TSTEPS 10

typedef __bf16 bf16x8 __attribute__((ext_vector_type(8)));
typedef float  f32x4  __attribute__((ext_vector_type(4)));
typedef unsigned short u16;

// fp32 -> bf16 round-to-nearest-even
__device__ __forceinline__ u16 f2bf(float v) {
    unsigned u = __float_as_uint(v);
    unsigned r = u + 0x7fffu + ((u >> 16) & 1u);
    return (u16)(r >> 16);
}

// ---------------------------------------------------------------------------
// flag init (d_ws is poisoned once, not re-poisoned between replays)
// ---------------------------------------------------------------------------
__global__ void init_flag_kernel(unsigned* flag) { *flag = 0u; }

// b2 == 0 detection: single block, 1024 floats, writes flag_b2 directly
__global__ void check_b2_kernel(const float* __restrict__ b2,
                                unsigned* __restrict__ flag_b2) {
    const int t = threadIdx.x;
    float4 v = ((const float4*)b2)[t];           // 256 threads x float4 = 1024
    bool nz = (v.x != 0.0f) | (v.y != 0.0f) | (v.z != 0.0f) | (v.w != 0.0f);
    unsigned long long m = __ballot(nz);
    __shared__ unsigned sh;
    if (t == 0) sh = 0u;
    __syncthreads();
    if ((t & 63) == 0 && m != 0ull) atomicOr(&sh, 1u);
    __syncthreads();
    if (t == 0) *flag_b2 = sh;
}

// ---------------------------------------------------------------------------
// streaming fp32 -> bf16 convert (W1 unconditional; W2/fc_W spike-conditional)
// ---------------------------------------------------------------------------
__global__ void cvt_bf16_kernel(const float* __restrict__ x,
                                u16* __restrict__ y, int n4) {
    int i0 = blockIdx.x * blockDim.x + threadIdx.x;
    int stride = gridDim.x * blockDim.x;
    for (int i = i0; i < n4; i += stride) {
        float4 v = ((const float4*)x)[i];
        ushort4 o;
        o.x = f2bf(v.x); o.y = f2bf(v.y); o.z = f2bf(v.z); o.w = f2bf(v.w);
        ((ushort4*)y)[i] = o;
    }
}

__global__ void cvt_bf16_cond_kernel(const unsigned* __restrict__ flag,
                                     const float* __restrict__ x,
                                     u16* __restrict__ y, int n4) {
    if (*flag == 0u) return;            // zero-spike: converted weights unused
    int i0 = blockIdx.x * blockDim.x + threadIdx.x;
    int stride = gridDim.x * blockDim.x;
    for (int i = i0; i < n4; i += stride) {
        float4 v = ((const float4*)x)[i];
        ushort4 o;
        o.x = f2bf(v.x); o.y = f2bf(v.y); o.z = f2bf(v.z); o.w = f2bf(v.w);
        ((ushort4*)y)[i] = o;
    }
}

// ---------------------------------------------------------------------------
// embedding gather + dropout mask -> bf16
// ---------------------------------------------------------------------------
__global__ void embed_bf16_kernel(const int* __restrict__ tok,
                                  const float* __restrict__ table,
                                  const float* __restrict__ mask,
                                  u16* __restrict__ ebf) {
    int i = blockIdx.x * blockDim.x + threadIdx.x;   // float4 index
    const int n4 = NB * NE / 4;
    if (i >= n4) return;
    int b = i / (NE / 4);
    int c = i % (NE / 4);
    float4 t = ((const float4*)(table + (size_t)tok[b] * NE))[c];
    float4 m = ((const float4*)mask)[i];
    ushort4 o;
    o.x = f2bf(t.x * m.x); o.y = f2bf(t.y * m.y);
    o.z = f2bf(t.z * m.z); o.w = f2bf(t.w * m.w);
    ((ushort4*)ebf)[i] = o;
}

// ---------------------------------------------------------------------------
// LIF recurrence -> hsum = mask_lif * sum_t spike_t (bf16) + spike flag.
// SNN spike-sparsity: if NO element of hsum is nonzero, the decode collapses
// (out = 10*b2 broadcast, linear = fc_b + 10*b2@fc_W^T broadcast).
// ---------------------------------------------------------------------------
__global__ void lif_bf16_flag_kernel(const float* __restrict__ delta1,
                                     const float* __restrict__ hidden,
                                     const float* __restrict__ mask_lif,
                                     const float* __restrict__ thr_p,
                                     const float* __restrict__ leak_p,
                                     u16* __restrict__ hbf,
                                     unsigned* __restrict__ flag) {
    int i = blockIdx.x * blockDim.x + threadIdx.x;
    if (i >= NB * NH / 4) return;
    const float thr = thr_p[0];
    const float leak = leak_p[0];
    float4 d4 = ((const float4*)delta1)[i];
    float4 m4 = ((const float4*)hidden)[i];
    float4 k4 = ((const float4*)mask_lif)[i];
    float dd[4] = {d4.x, d4.y, d4.z, d4.w};
    float mm[4] = {m4.x, m4.y, m4.z, m4.w};
    float kk[4] = {k4.x, k4.y, k4.z, k4.w};
    ushort4 o;
    u16 oo[4];
    bool nz = false;
#pragma unroll
    for (int j = 0; j < 4; ++j) {
        float m = mm[j], cnt = 0.0f;
#pragma unroll
        for (int t = 0; t < TSTEPS; ++t) {
            float mem = leak * m + dd[j];
            float s = ((mem / thr - 1.0f) > 0.0f) ? 1.0f : 0.0f;
            m = mem - thr * s;
            cnt += s;
        }
        float v = cnt * kk[j];
        nz |= (v != 0.0f);
        oo[j] = f2bf(v);
    }
    o.x = oo[0]; o.y = oo[1]; o.z = oo[2]; o.w = oo[3];
    ((ushort4*)hbf)[i] = o;
    if (nz) atomicOr(flag, 1u);          // device-scope; wave-coalesced (G12)
}

// ---------------------------------------------------------------------------
// zero-spike fast path kernels (run iff flag_spike == 0)
// ---------------------------------------------------------------------------
// out = 10*b2 broadcast over rows (fp32 second output; bf16 mirror unused here)
__global__ void bcast_out_kernel(const unsigned* __restrict__ flag,
                                 const float* __restrict__ b2,
                                 float* __restrict__ outbuf) {
    if (*flag != 0u) return;
    int i0 = blockIdx.x * blockDim.x + threadIdx.x;
    int stride = gridDim.x * blockDim.x;
    const int n4 = NB * NH / 4;
    for (int i = i0; i < n4; i += stride) {
        int h4 = i & (NH / 4 - 1);
        float4 v = ((const float4*)b2)[h4];
        v.x *= (float)TSTEPS; v.y *= (float)TSTEPS;
        v.z *= (float)TSTEPS; v.w *= (float)TSTEPS;
        ((float4*)outbuf)[i] = v;
    }
}

// y = fc_b  (b2 == 0 shortcut: skips the whole 206 MB fc_W scan)
__global__ void y_fcb_kernel(const unsigned* __restrict__ flag,
                             const unsigned* __restrict__ flag_b2,
                             const float* __restrict__ fc_b,
                             float* __restrict__ y) {
    if (*flag != 0u || *flag_b2 != 0u) return;
    int i = blockIdx.x * blockDim.x + threadIdx.x;
    if (i < NV) y[i] = fc_b[i];
}

// y[v] = fc_b[v] + 10 * dot(b2, fc_W[v,:])  — one wave per column (b2 != 0)
__global__ void matvec_fc_kernel(const unsigned* __restrict__ flag,
                                 const unsigned* __restrict__ flag_b2,
                                 const float* __restrict__ b2,
                                 const float* __restrict__ fcW,
                                 const float* __restrict__ fc_b,
                                 float* __restrict__ y) {
    if (*flag != 0u || *flag_b2 == 0u) return;
    const int col = blockIdx.x * 4 + (threadIdx.x >> 6);
    const int l = threadIdx.x & 63;
    if (col >= NV) return;
    const float4* row = (const float4*)(fcW + (size_t)col * NH);
    const float4* bb = (const float4*)b2;
    float s = 0.0f;
#pragma unroll
    for (int it = 0; it < NH / 256; ++it) {      // 4 iters of 64 float4
        float4 v = row[it * 64 + l];
        float4 b = bb[it * 64 + l];
        s += v.x * b.x + v.y * b.y + v.z * b.z + v.w * b.w;
    }
#pragma unroll
    for (int off = 32; off > 0; off >>= 1) s += __shfl_down(s, off);
    if (l == 0) y[col] = fc_b[col] + (float)TSTEPS * s;
}

// linear[b, v] = y[v] broadcast over all rows (coalesced row-major writes)
__global__ void bcast_linear_kernel(const unsigned* __restrict__ flag,
                                    const float* __restrict__ y,
                                    float* __restrict__ linear) {
    if (*flag != 0u) return;
    const int c0 = blockIdx.x * 1024;            // column chunk
    const int r0 = blockIdx.y * 4;               // 4 rows per block
    const int t = threadIdx.x;
    float vy[4];
#pragma unroll
    for (int k = 0; k < 4; ++k) {
        int c = c0 + t + k * 256;
        vy[k] = (c < NV) ? y[c] : 0.0f;
    }
#pragma unroll
    for (int r = 0; r < 4; ++r) {
        float* dst = linear + (size_t)(r0 + r) * NV;
#pragma unroll
        for (int k = 0; k < 4; ++k) {
            int c = c0 + t + k * 256;
            if (c < NV) dst[c] = vy[k];
        }
    }
}

// ---------------------------------------------------------------------------
// bf16 x bf16 MFMA GEMM (round-9 pipeline, best measured: counted vmcnt,
// DEPTH=3, wave-tile 64 x (TBN/2), XCD-grouped 1D grid). C = A*B^T + bias*s.
// - Fragment-linear LDS (1KB units, lane l -> row l&15, k (l>>4)*8):
//   conflict-free ds_read_b128 (measured SQ_LDS_BANK_CONFLICT = 0).
// - vmcnt(PER) steady / vmcnt(0) last iter (round-7 tail race fixed),
//   one s_barrier per step, stage(t+2) -> buffer last read at t-1.
// - XCD grouping (verified: FETCH 415->99 MB). REQUIRES M/TBM == 8.
// NOTE: concrete __global__ wrappers (template __global__ fails to link).
// ---------------------------------------------------------------------------
template<int TBM, int TBN, int NWAVE>
__device__ __forceinline__
void gemm_pipe2_body(const u16* __restrict__ Abf, const u16* __restrict__ Bbf,
                     const float* __restrict__ bias, float bias_scale,
                     float* __restrict__ C, u16* __restrict__ Cb,
                     int M, int N, int K) {
    constexpr int AU = TBM / 16;
    constexpr int BU = TBN / 16;
    constexpr int TOT = AU + BU;
    constexpr int PER = TOT / NWAVE;
    constexpr int MF = 4;
    constexpr int NF = TBN / 32;
    constexpr int DEPTH = 3;
    static_assert(TOT % NWAVE == 0, "unit split");
    static_assert(NWAVE == 4 && TBM == 128, "wave tiling: 2x2 waves");

    __shared__ u16 sA[DEPTH][AU * 512];
    __shared__ u16 sB[DEPTH][BU * 512];

    const int i = blockIdx.x;
    const int xcd = i & 7;
    const int rb  = (i >> 3) & 7;
    const int p   = ((i >> 6) << 3) + xcd;
    if (p * TBN >= N) return;               // padded-grid guard (before barriers)
    const int bm = rb * TBM;
    const int bn = p * TBN;

    const int tid = threadIdx.x;
    const int w = tid >> 6;
    const int l = tid & 63;
    const int wr16 = (w >> 1) * MF;
    const int wc16 = (w & 1) * NF;
    const int lrow = l & 15;
    const int lk8 = (l >> 4) * 8;
    const int l8 = l * 8;

    f32x4 acc[MF][NF];
#pragma unroll
    for (int m = 0; m < MF; ++m)
#pragma unroll
        for (int n = 0; n < NF; ++n)
#pragma unroll
            for (int q = 0; q < 4; ++q) acc[m][n][q] = 0.0f;

    const int NT = K / 32;

    auto stage = [&](int buf, int k0) {
#pragma unroll
        for (int s = 0; s < PER; ++s) {
            const int c = w * PER + s;
            if (c < AU) {
                const int row = bm + c * 16 + lrow;
                __builtin_amdgcn_global_load_lds(Abf + (size_t)row * K + k0 + lk8,
                                                 &sA[buf][c * 512], 16, 0, 0);
            } else {
                const int u = c - AU;
                int row = bn + u * 16 + lrow; if (row >= N) row = N - 1;
                __builtin_amdgcn_global_load_lds(Bbf + (size_t)row * K + k0 + lk8,
                                                 &sB[buf][u * 512], 16, 0, 0);
            }
        }
    };

    stage(0, 0);
    stage(1, 32);

    int cur = 0;
    for (int t = 0; t < NT; ++t) {
        if (t + 1 < NT) {
            asm volatile("s_waitcnt vmcnt(%0)" :: "n"(PER) : "memory");
        } else {
            asm volatile("s_waitcnt vmcnt(0)" ::: "memory");
        }
        __builtin_amdgcn_sched_barrier(0);
        __builtin_amdgcn_s_barrier();
        __builtin_amdgcn_sched_barrier(0);

        if (t + 2 < NT) {
            int nb = cur + 2; if (nb >= DEPTH) nb -= DEPTH;
            stage(nb, (t + 2) * 32);
        }

        bf16x8 ah[MF], bh[NF];
#pragma unroll
        for (int m = 0; m < MF; ++m)
            ah[m] = *(const bf16x8*)&sA[cur][(wr16 + m) * 512 + l8];
#pragma unroll
        for (int n = 0; n < NF; ++n)
            bh[n] = *(const bf16x8*)&sB[cur][(wc16 + n) * 512 + l8];

#pragma unroll
        for (int m = 0; m < MF; ++m)
#pragma unroll
            for (int n = 0; n < NF; ++n)
                acc[m][n] = __builtin_amdgcn_mfma_f32_16x16x32_bf16(ah[m], bh[n], acc[m][n], 0, 0, 0);

        __builtin_amdgcn_sched_barrier(0);
        cur = (cur + 1 == DEPTH) ? 0 : cur + 1;
    }

    const int lq = (l >> 4) * 4;
    const int wrow = bm + (w >> 1) * 64;
    const int wcol = bn + (w & 1) * (NF * 16);
#pragma unroll
    for (int n = 0; n < NF; ++n) {
        const int gcol = wcol + n * 16 + (l & 15);
        if (gcol >= N) continue;
        const float bb = bias[gcol] * bias_scale;
#pragma unroll
        for (int m = 0; m < MF; ++m) {
            const int grow = wrow + m * 16 + lq;
#pragma unroll
            for (int q = 0; q < 4; ++q) {
                float v = acc[m][n][q] + bb;
                C[(size_t)(grow + q) * N + gcol] = v;
                if (Cb) Cb[(size_t)(grow + q) * N + gcol] = f2bf(v);
            }
        }
    }
}

// unconditional (kernel 1)
__global__ __launch_bounds__(256)
void gemm_pipe2_128(const u16* __restrict__ Abf, const u16* __restrict__ Bbf,
                    const float* __restrict__ bias, float bias_scale,
                    float* __restrict__ C, u16* __restrict__ Cb, int M, int N, int K) {
    gemm_pipe2_body<128, 128, 4>(Abf, Bbf, bias, bias_scale, C, Cb, M, N, K);
}

// conditional: run only when spikes fired (flag != 0)
__global__ __launch_bounds__(256)
void gemm_pipe2_128_cond(const unsigned* __restrict__ flag,
                         const u16* __restrict__ Abf, const u16* __restrict__ Bbf,
                         const float* __restrict__ bias, float bias_scale,
                         float* __restrict__ C, u16* __restrict__ Cb, int M, int N, int K) {
    if (*flag == 0u) return;
    gemm_pipe2_body<128, 128, 4>(Abf, Bbf, bias, bias_scale, C, Cb, M, N, K);
}

__global__ __launch_bounds__(256, 2)
void gemm_pipe2_256_cond(const unsigned* __restrict__ flag,
                         const u16* __restrict__ Abf, const u16* __restrict__ Bbf,
                         const float* __restrict__ bias, float bias_scale,
                         float* __restrict__ C, u16* __restrict__ Cb, int M, int N, int K) {
    if (*flag == 0u) return;
    gemm_pipe2_body<128, 256, 4>(Abf, Bbf, bias, bias_scale, C, Cb, M, N, K);
}

// ---------------------------------------------------------------------------
// fp32 fallback kernels (tiny-workspace safety net)
// ---------------------------------------------------------------------------
__global__ void embed_kernel(const int* __restrict__ tok,
                             const float* __restrict__ table,
                             const float* __restrict__ mask,
                             float* __restrict__ emb) {
    int i = blockIdx.x * blockDim.x + threadIdx.x;
    const int n4 = NB * NE / 4;
    if (i >= n4) return;
    int b = i / (NE / 4);
    int c = i % (NE / 4);
    float4 t = ((const float4*)(table + (size_t)tok[b] * NE))[c];
    float4 m = ((const float4*)mask)[i];
    float4 o;
    o.x = t.x * m.x; o.y = t.y * m.y; o.z = t.z * m.z; o.w = t.w * m.w;
    ((float4*)emb)[i] = o;
}

__global__ void lif_kernel(const float* __restrict__ delta1,
                           const float* __restrict__ hidden,
                           const float* __restrict__ mask_lif,
                           const float* __restrict__ thr_p,
                           const float* __restrict__ leak_p,
                           float* __restrict__ hsum) {
    int i = blockIdx.x * blockDim.x + threadIdx.x;
    if (i >= NB * NH) return;
    const float thr = thr_p[0];
    const float leak = leak_p[0];
    float d = delta1[i];
    float m = hidden[i];
    float cnt = 0.0f;
#pragma unroll
    for (int t = 0; t < TSTEPS; ++t) {
        float mem = leak * m + d;
        float s = ((mem / thr - 1.0f) > 0.0f) ? 1.0f : 0.0f;
        m = mem - thr * s;
        cnt += s;
    }
    hsum[i] = cnt * mask_lif[i];
}

#define BM 128
#define BN 128
#define BK 16

__global__ __launch_bounds__(256)
void gemm_nt(const float* __restrict__ A, const float* __restrict__ Bm,
             const float* __restrict__ bias, float bias_scale,
             float* __restrict__ C, int M, int N, int K) {
    __shared__ float As[BK][BM + 4];
    __shared__ float Bs[BK][BN + 4];

    const int tid = threadIdx.x;
    const int bm = blockIdx.y * BM;
    const int bn = blockIdx.x * BN;
    const int tx = tid & 15;
    const int ty = tid >> 4;
    const int tm = ty * 8;
    const int tn0 = tx * 4;
    const int tn1 = 64 + tx * 4;

    float acc[8][8];
#pragma unroll
    for (int i = 0; i < 8; ++i)
#pragma unroll
        for (int j = 0; j < 8; ++j) acc[i][j] = 0.0f;

    constexpr int LDA4 = BK / 4;

    for (int k0 = 0; k0 < K; k0 += BK) {
#pragma unroll
        for (int idx = tid; idx < BM * LDA4; idx += 256) {
            int m = idx / LDA4, c = idx % LDA4;
            float4 v = *(const float4*)(A + (size_t)(bm + m) * K + k0 + c * 4);
            As[c * 4 + 0][m] = v.x;
            As[c * 4 + 1][m] = v.y;
            As[c * 4 + 2][m] = v.z;
            As[c * 4 + 3][m] = v.w;
        }
#pragma unroll
        for (int idx = tid; idx < BN * LDA4; idx += 256) {
            int n = idx / LDA4, c = idx % LDA4;
            float4 v = make_float4(0.f, 0.f, 0.f, 0.f);
            int gn = bn + n;
            if (gn < N) v = *(const float4*)(Bm + (size_t)gn * K + k0 + c * 4);
            Bs[c * 4 + 0][n] = v.x;
            Bs[c * 4 + 1][n] = v.y;
            Bs[c * 4 + 2][n] = v.z;
            Bs[c * 4 + 3][n] = v.w;
        }
        __syncthreads();

#pragma unroll
        for (int k = 0; k < BK; ++k) {
            float4 a0 = *(const float4*)&As[k][tm];
            float4 a1 = *(const float4*)&As[k][tm + 4];
            float4 b0 = *(const float4*)&Bs[k][tn0];
            float4 b1 = *(const float4*)&Bs[k][tn1];
            float a[8] = {a0.x, a0.y, a0.z, a0.w, a1.x, a1.y, a1.z, a1.w};
            float bb[8] = {b0.x, b0.y, b0.z, b0.w, b1.x, b1.y, b1.z, b1.w};
#pragma unroll
            for (int i = 0; i < 8; ++i)
#pragma unroll
                for (int j = 0; j < 8; ++j)
                    acc[i][j] = fmaf(a[i], bb[j], acc[i][j]);
        }
        __syncthreads();
    }

#pragma unroll
    for (int i = 0; i < 8; ++i) {
        size_t row = (size_t)(bm + tm + i) * N;
#pragma unroll
        for (int j = 0; j < 8; ++j) {
            int gn = bn + ((j < 4) ? (tn0 + j) : (tn1 + j - 4));
            if (gn < N)
                C[row + gn] = acc[i][j] + bias[gn] * bias_scale;
        }
    }
}

// ---------------------------------------------------------------------------
static inline int grid1d(int N, int TBN) {
    int P = (N + TBN - 1) / TBN;
    int P8 = ((P + 7) / 8) * 8;
    return 8 * P8;                  // 8 row-blocks x padded panels
}

extern "C" void kernel_launch(void* const* d_in, const int* in_sizes, int n_in,
                              void* d_out, int out_size, void* d_ws, size_t ws_size,
                              hipStream_t stream) {
    const int*   tok      = (const int*)  d_in[0];
    const float* hidden   = (const float*)d_in[1];
    const float* table    = (const float*)d_in[2];
    const float* W1       = (const float*)d_in[3];
    const float* b1       = (const float*)d_in[4];
    const float* W2       = (const float*)d_in[5];
    const float* b2       = (const float*)d_in[6];
    const float* fc_W     = (const float*)d_in[7];
    const float* fc_b     = (const float*)d_in[8];
    const float* thr      = (const float*)d_in[9];
    const float* leak     = (const float*)d_in[10];
    const float* mask_emb = (const float*)d_in[11];
    const float* mask_lif = (const float*)d_in[12];

    float* linear = (float*)d_out;                   // [B,V]
    float* outbuf = (float*)d_out + (size_t)NB * NV; // [B,H]

    const size_t SZ_FLAG = 16;                   // two flags live here
    const size_t SZ_Y   = ((size_t)NV * 4 + 15) / 16 * 16;  // y[V]
    const size_t SZ_EB  = (size_t)NB * NE * 2;   // ebf
    const size_t SZ_D1  = (size_t)NB * NH * 4;   // delta1 fp32
    const size_t SZ_HB  = (size_t)NB * NH * 2;   // hbf
    const size_t SZ_OB  = (size_t)NB * NH * 2;   // obf
    const size_t SZ_W1B = (size_t)NH * NE * 2;   // W1 bf16
    const size_t SZ_W2B = (size_t)NH * NH * 2;   // W2 bf16
    const size_t SZ_WB  = (size_t)NV * NH * 2;   // fc_W bf16 (~103 MB)
    const size_t need_bf = SZ_FLAG + SZ_Y + SZ_EB + SZ_D1 + SZ_HB + SZ_OB
                         + SZ_W1B + SZ_W2B + SZ_WB;

    char* p = (char*)d_ws;

    if (ws_size >= need_bf) {
        unsigned* flag    = (unsigned*)p;            // [0] spike, [1] b2-nonzero
        unsigned* flag_b2 = (unsigned*)p + 1;
        p += SZ_FLAG;
        float* y      = (float*)p;     p += SZ_Y;
        u16*   ebf    = (u16*)p;       p += SZ_EB;
        float* delta1 = (float*)p;     p += SZ_D1;
        u16*   hbf    = (u16*)p;       p += SZ_HB;
        u16*   obf    = (u16*)p;       p += SZ_OB;
        u16*   w1b    = (u16*)p;       p += SZ_W1B;
        u16*   w2b    = (u16*)p;       p += SZ_W2B;
        u16*   fcwb   = (u16*)p;       p += SZ_WB;

        // flags
        init_flag_kernel<<<1, 1, 0, stream>>>(flag);
        check_b2_kernel<<<1, 256, 0, stream>>>(b2, flag_b2);
        // W1 convert (always needed for kernel 1)
        cvt_bf16_kernel<<<512, 256, 0, stream>>>(W1, w1b, NH * NE / 4);
        // 0: embedding gather + mask -> bf16
        {
            int n4 = NB * NE / 4;
            embed_bf16_kernel<<<(n4 + 255) / 256, 256, 0, stream>>>(tok, table, mask_emb, ebf);
        }
        // 1: delta1 = ebf @ w1b^T + b1   (M=B, N=H, K=E) — always
        gemm_pipe2_128<<<grid1d(NH, 128), 256, 0, stream>>>(ebf, w1b, b1, 1.0f,
                                                            delta1, (u16*)nullptr, NB, NH, NE);
        // 2: LIF -> hbf (bf16) + spike flag
        {
            int n = NB * NH / 4;
            lif_bf16_flag_kernel<<<(n + 255) / 256, 256, 0, stream>>>(delta1, hidden, mask_lif,
                                                                      thr, leak, hbf, flag);
        }
        // ---- spike path (flag != 0): full MFMA decode ----
        cvt_bf16_cond_kernel<<<512, 256, 0, stream>>>(flag, W2, w2b, NH * NH / 4);
        cvt_bf16_cond_kernel<<<2048, 256, 0, stream>>>(flag, fc_W, fcwb, NV * NH / 4);
        gemm_pipe2_128_cond<<<grid1d(NH, 128), 256, 0, stream>>>(flag, hbf, w2b, b2, (float)TSTEPS,
                                                                 outbuf, obf, NB, NH, NH);
        gemm_pipe2_256_cond<<<grid1d(NV, 256), 256, 0, stream>>>(flag, obf, fcwb, fc_b, 1.0f,
                                                                 linear, (u16*)nullptr, NB, NV, NH);
        // ---- zero-spike fast path (flag == 0) ----
        bcast_out_kernel<<<1024, 256, 0, stream>>>(flag, b2, outbuf);
        y_fcb_kernel<<<(NV + 255) / 256, 256, 0, stream>>>(flag, flag_b2, fc_b, y);
        matvec_fc_kernel<<<(NV + 3) / 4, 256, 0, stream>>>(flag, flag_b2, b2, fc_W, fc_b, y);
        {
            dim3 grid((NV + 1023) / 1024, NB / 4);
            bcast_linear_kernel<<<grid, 256, 0, stream>>>(flag, y, linear);
        }
    } else {
        // ----- pure fp32 fallback -----
        float* emb    = (float*)p;  p += (size_t)NB * NE * 4;
        float* delta1 = (float*)p;  p += SZ_D1;
        float* hsum   = (float*)p;

        int n4 = NB * NE / 4;
        embed_kernel<<<(n4 + 255) / 256, 256, 0, stream>>>(tok, table, mask_emb, emb);
        {
            dim3 grid(NH / BN, NB / BM);
            gemm_nt<<<grid, 256, 0, stream>>>(emb, W1, b1, 1.0f, delta1, NB, NH, NE);
        }
        {
            int n = NB * NH;
            lif_kernel<<<(n + 255) / 256, 256, 0, stream>>>(delta1, hidden, mask_lif,
                                                            thr, leak, hsum);
        }
        {
            dim3 grid(NH / BN, NB / BM);
            gemm_nt<<<grid, 256, 0, stream>>>(hsum, W2, b2, (float)TSTEPS, outbuf, NB, NH, NH);
        }
        {
            dim3 grid((NV + BN - 1) / BN, NB / BM);
            gemm_nt<<<grid, 256, 0, stream>>>(outbuf, fc_W, fc_b, 1.0f, linear, NB, NV, NH);
        }
    }
}

// Round 13
// 74.325 us; speedup vs baseline: 8.3735x; 1.1066x over previous
//
#include <hip/hip_runtime.h>

#define NV 50257
#define NE 512
#define NH 1024
#define NB 1024
#define TSTEPS 10

typedef __bf16 bf16x8 __attribute__((ext_vector_type(8)));
typedef float  f32x4  __attribute__((ext_vector_type(4)));
typedef unsigned short u16;

// fp32 -> bf16 round-to-nearest-even
__device__ __forceinline__ u16 f2bf(float v) {
    unsigned u = __float_as_uint(v);
    unsigned r = u + 0x7fffu + ((u >> 16) & 1u);
    return (u16)(r >> 16);
}

// ---------------------------------------------------------------------------
// init: flag=0 (ws not re-poisoned between replays) + b2==0 detection.
// One block, 256 threads x float4 = all 1024 b2 elements.
// ---------------------------------------------------------------------------
__global__ void init_kernel(const float* __restrict__ b2,
                            unsigned* __restrict__ flag,
                            unsigned* __restrict__ flag_b2) {
    const int t = threadIdx.x;
    float4 v = ((const float4*)b2)[t];
    bool nz = (v.x != 0.0f) | (v.y != 0.0f) | (v.z != 0.0f) | (v.w != 0.0f);
    unsigned long long m = __ballot(nz);
    __shared__ unsigned sh;
    if (t == 0) sh = 0u;
    __syncthreads();
    if ((t & 63) == 0 && m != 0ull) atomicOr(&sh, 1u);
    __syncthreads();
    if (t == 0) { *flag = 0u; *flag_b2 = sh; }
}

// ---------------------------------------------------------------------------
// merged: blocks [0,512) convert W1 -> bf16; blocks [512,1024) embed+mask.
// Both jobs are exactly 131072 float4s = 512 blocks x 256 threads x 1.
// ---------------------------------------------------------------------------
__global__ void prep_kernel(const float* __restrict__ W1, u16* __restrict__ w1b,
                            const int* __restrict__ tok,
                            const float* __restrict__ table,
                            const float* __restrict__ mask,
                            u16* __restrict__ ebf) {
    const int b = blockIdx.x;
    if (b < 512) {                       // W1 convert
        int i = b * 256 + threadIdx.x;   // float4 index, n4 = 512*1024/4
        float4 v = ((const float4*)W1)[i];
        ushort4 o;
        o.x = f2bf(v.x); o.y = f2bf(v.y); o.z = f2bf(v.z); o.w = f2bf(v.w);
        ((ushort4*)w1b)[i] = o;
    } else {                             // embedding gather + dropout mask
        int i = (b - 512) * 256 + threadIdx.x;   // n4 = 1024*512/4
        int bb = i / (NE / 4);
        int c = i % (NE / 4);
        float4 t = ((const float4*)(table + (size_t)tok[bb] * NE))[c];
        float4 m = ((const float4*)mask)[i];
        ushort4 o;
        o.x = f2bf(t.x * m.x); o.y = f2bf(t.y * m.y);
        o.z = f2bf(t.z * m.z); o.w = f2bf(t.w * m.w);
        ((ushort4*)ebf)[i] = o;
    }
}

// ---------------------------------------------------------------------------
// LIF recurrence -> hsum = mask_lif * sum_t spike_t (bf16) + spike flag.
// SNN spike-sparsity: if NO element of hsum is nonzero, the decode collapses.
// ---------------------------------------------------------------------------
__global__ void lif_bf16_flag_kernel(const float* __restrict__ delta1,
                                     const float* __restrict__ hidden,
                                     const float* __restrict__ mask_lif,
                                     const float* __restrict__ thr_p,
                                     const float* __restrict__ leak_p,
                                     u16* __restrict__ hbf,
                                     unsigned* __restrict__ flag) {
    int i = blockIdx.x * blockDim.x + threadIdx.x;
    if (i >= NB * NH / 4) return;
    const float thr = thr_p[0];
    const float leak = leak_p[0];
    float4 d4 = ((const float4*)delta1)[i];
    float4 m4 = ((const float4*)hidden)[i];
    float4 k4 = ((const float4*)mask_lif)[i];
    float dd[4] = {d4.x, d4.y, d4.z, d4.w};
    float mm[4] = {m4.x, m4.y, m4.z, m4.w};
    float kk[4] = {k4.x, k4.y, k4.z, k4.w};
    ushort4 o;
    u16 oo[4];
    bool nz = false;
#pragma unroll
    for (int j = 0; j < 4; ++j) {
        float m = mm[j], cnt = 0.0f;
#pragma unroll
        for (int t = 0; t < TSTEPS; ++t) {
            float mem = leak * m + dd[j];
            float s = ((mem / thr - 1.0f) > 0.0f) ? 1.0f : 0.0f;
            m = mem - thr * s;
            cnt += s;
        }
        float v = cnt * kk[j];
        nz |= (v != 0.0f);
        oo[j] = f2bf(v);
    }
    o.x = oo[0]; o.y = oo[1]; o.z = oo[2]; o.w = oo[3];
    ((ushort4*)hbf)[i] = o;
    if (nz) atomicOr(flag, 1u);          // device-scope; wave-coalesced (G12)
}

// ---------------------------------------------------------------------------
// spike-path weight converts (merged W2 + fc_W), runs iff flag != 0
// ---------------------------------------------------------------------------
__global__ void cvt_cond_kernel(const unsigned* __restrict__ flag,
                                const float* __restrict__ W2, u16* __restrict__ w2b,
                                const float* __restrict__ fcW, u16* __restrict__ fcwb) {
    if (*flag == 0u) return;
    const int b = blockIdx.x;
    if (b < 512) {                       // W2: n4 = 262144, grid-stride by 512 blk
        for (int i = b * 256 + threadIdx.x; i < NH * NH / 4; i += 512 * 256) {
            float4 v = ((const float4*)W2)[i];
            ushort4 o;
            o.x = f2bf(v.x); o.y = f2bf(v.y); o.z = f2bf(v.z); o.w = f2bf(v.w);
            ((ushort4*)w2b)[i] = o;
        }
    } else {                             // fc_W: n4 = 12865792, 2048 blocks
        for (int i = (b - 512) * 256 + threadIdx.x; i < NV * NH / 4; i += 2048 * 256) {
            float4 v = ((const float4*)fcW)[i];
            ushort4 o;
            o.x = f2bf(v.x); o.y = f2bf(v.y); o.z = f2bf(v.z); o.w = f2bf(v.w);
            ((ushort4*)fcwb)[i] = o;
        }
    }
}

// ---------------------------------------------------------------------------
// zero-spike fast path kernels (run iff flag == 0)
// ---------------------------------------------------------------------------
// out = 10*b2 broadcast over rows (fp32 second output)
__global__ void bcast_out_kernel(const unsigned* __restrict__ flag,
                                 const float* __restrict__ b2,
                                 float* __restrict__ outbuf) {
    if (*flag != 0u) return;
    int i0 = blockIdx.x * blockDim.x + threadIdx.x;
    int stride = gridDim.x * blockDim.x;
    const int n4 = NB * NH / 4;
    for (int i = i0; i < n4; i += stride) {
        int h4 = i & (NH / 4 - 1);
        float4 v = ((const float4*)b2)[h4];
        v.x *= (float)TSTEPS; v.y *= (float)TSTEPS;
        v.z *= (float)TSTEPS; v.w *= (float)TSTEPS;
        ((float4*)outbuf)[i] = v;
    }
}

// y[v] = fc_b[v] + 10 * dot(b2, fc_W[v,:]) — persistent: 2048 blocks, wave
// per column, grid-stride (cheap drain when disabled). Runs iff spikes==0
// AND b2 != 0.
__global__ void matvec_fc_kernel(const unsigned* __restrict__ flag,
                                 const unsigned* __restrict__ flag_b2,
                                 const float* __restrict__ b2,
                                 const float* __restrict__ fcW,
                                 const float* __restrict__ fc_b,
                                 float* __restrict__ y) {
    if (*flag != 0u || *flag_b2 == 0u) return;
    const int wid = (blockIdx.x * 256 + threadIdx.x) >> 6;   // 0..8191
    const int l = threadIdx.x & 63;
    const float4* bb = (const float4*)b2;
    for (int col = wid; col < NV; col += 2048 * 4) {
        const float4* row = (const float4*)(fcW + (size_t)col * NH);
        float s = 0.0f;
#pragma unroll
        for (int it = 0; it < NH / 256; ++it) {
            float4 v = row[it * 64 + l];
            float4 b = bb[it * 64 + l];
            s += v.x * b.x + v.y * b.y + v.z * b.z + v.w * b.w;
        }
#pragma unroll
        for (int off = 32; off > 0; off >>= 1) s += __shfl_down(s, off);
        if (l == 0) y[col] = fc_b[col] + (float)TSTEPS * s;
    }
}

// linear[b, v] = src[v] broadcast; src = y (b2 != 0) or fc_b directly
// (b2 == 0 — skips the y materialization pass entirely)
__global__ void bcast_linear_kernel(const unsigned* __restrict__ flag,
                                    const unsigned* __restrict__ flag_b2,
                                    const float* __restrict__ y,
                                    const float* __restrict__ fc_b,
                                    float* __restrict__ linear) {
    if (*flag != 0u) return;
    const float* __restrict__ src = (*flag_b2 != 0u) ? y : fc_b;
    const int c0 = blockIdx.x * 1024;            // column chunk
    const int r0 = blockIdx.y * 8;               // 8 rows per block
    const int t = threadIdx.x;
    float vy[4];
#pragma unroll
    for (int k = 0; k < 4; ++k) {
        int c = c0 + t + k * 256;
        vy[k] = (c < NV) ? src[c] : 0.0f;
    }
#pragma unroll
    for (int r = 0; r < 8; ++r) {
        float* dst = linear + (size_t)(r0 + r) * NV;
#pragma unroll
        for (int k = 0; k < 4; ++k) {
            int c = c0 + t + k * 256;
            if (c < NV) dst[c] = vy[k];
        }
    }
}

// ---------------------------------------------------------------------------
// bf16 x bf16 MFMA GEMM (round-9 pipeline, best measured: counted vmcnt,
// DEPTH=3, wave-tile 64 x (TBN/2), XCD-grouped 1D grid). C = A*B^T + bias*s.
// - Fragment-linear LDS (1KB units, lane l -> row l&15, k (l>>4)*8):
//   conflict-free ds_read_b128 (measured SQ_LDS_BANK_CONFLICT = 0).
// - vmcnt(PER) steady / vmcnt(0) last iter (round-7 tail race fixed),
//   one s_barrier per step, stage(t+2) -> buffer last read at t-1.
// - XCD grouping (verified: FETCH 415->99 MB). REQUIRES M/TBM == 8.
// NOTE: concrete __global__ wrappers (template __global__ fails to link).
// ---------------------------------------------------------------------------
template<int TBM, int TBN, int NWAVE>
__device__ __forceinline__
void gemm_pipe2_body(const u16* __restrict__ Abf, const u16* __restrict__ Bbf,
                     const float* __restrict__ bias, float bias_scale,
                     float* __restrict__ C, u16* __restrict__ Cb,
                     int M, int N, int K) {
    constexpr int AU = TBM / 16;
    constexpr int BU = TBN / 16;
    constexpr int TOT = AU + BU;
    constexpr int PER = TOT / NWAVE;
    constexpr int MF = 4;
    constexpr int NF = TBN / 32;
    constexpr int DEPTH = 3;
    static_assert(TOT % NWAVE == 0, "unit split");
    static_assert(NWAVE == 4 && TBM == 128, "wave tiling: 2x2 waves");

    __shared__ u16 sA[DEPTH][AU * 512];
    __shared__ u16 sB[DEPTH][BU * 512];

    const int i = blockIdx.x;
    const int xcd = i & 7;
    const int rb  = (i >> 3) & 7;
    const int p   = ((i >> 6) << 3) + xcd;
    if (p * TBN >= N) return;               // padded-grid guard (before barriers)
    const int bm = rb * TBM;
    const int bn = p * TBN;

    const int tid = threadIdx.x;
    const int w = tid >> 6;
    const int l = tid & 63;
    const int wr16 = (w >> 1) * MF;
    const int wc16 = (w & 1) * NF;
    const int lrow = l & 15;
    const int lk8 = (l >> 4) * 8;
    const int l8 = l * 8;

    f32x4 acc[MF][NF];
#pragma unroll
    for (int m = 0; m < MF; ++m)
#pragma unroll
        for (int n = 0; n < NF; ++n)
#pragma unroll
            for (int q = 0; q < 4; ++q) acc[m][n][q] = 0.0f;

    const int NT = K / 32;

    auto stage = [&](int buf, int k0) {
#pragma unroll
        for (int s = 0; s < PER; ++s) {
            const int c = w * PER + s;
            if (c < AU) {
                const int row = bm + c * 16 + lrow;
                __builtin_amdgcn_global_load_lds(Abf + (size_t)row * K + k0 + lk8,
                                                 &sA[buf][c * 512], 16, 0, 0);
            } else {
                const int u = c - AU;
                int row = bn + u * 16 + lrow; if (row >= N) row = N - 1;
                __builtin_amdgcn_global_load_lds(Bbf + (size_t)row * K + k0 + lk8,
                                                 &sB[buf][u * 512], 16, 0, 0);
            }
        }
    };

    stage(0, 0);
    stage(1, 32);

    int cur = 0;
    for (int t = 0; t < NT; ++t) {
        if (t + 1 < NT) {
            asm volatile("s_waitcnt vmcnt(%0)" :: "n"(PER) : "memory");
        } else {
            asm volatile("s_waitcnt vmcnt(0)" ::: "memory");
        }
        __builtin_amdgcn_sched_barrier(0);
        __builtin_amdgcn_s_barrier();
        __builtin_amdgcn_sched_barrier(0);

        if (t + 2 < NT) {
            int nb = cur + 2; if (nb >= DEPTH) nb -= DEPTH;
            stage(nb, (t + 2) * 32);
        }

        bf16x8 ah[MF], bh[NF];
#pragma unroll
        for (int m = 0; m < MF; ++m)
            ah[m] = *(const bf16x8*)&sA[cur][(wr16 + m) * 512 + l8];
#pragma unroll
        for (int n = 0; n < NF; ++n)
            bh[n] = *(const bf16x8*)&sB[cur][(wc16 + n) * 512 + l8];

#pragma unroll
        for (int m = 0; m < MF; ++m)
#pragma unroll
            for (int n = 0; n < NF; ++n)
                acc[m][n] = __builtin_amdgcn_mfma_f32_16x16x32_bf16(ah[m], bh[n], acc[m][n], 0, 0, 0);

        __builtin_amdgcn_sched_barrier(0);
        cur = (cur + 1 == DEPTH) ? 0 : cur + 1;
    }

    const int lq = (l >> 4) * 4;
    const int wrow = bm + (w >> 1) * 64;
    const int wcol = bn + (w & 1) * (NF * 16);
#pragma unroll
    for (int n = 0; n < NF; ++n) {
        const int gcol = wcol + n * 16 + (l & 15);
        if (gcol >= N) continue;
        const float bb = bias[gcol] * bias_scale;
#pragma unroll
        for (int m = 0; m < MF; ++m) {
            const int grow = wrow + m * 16 + lq;
#pragma unroll
            for (int q = 0; q < 4; ++q) {
                float v = acc[m][n][q] + bb;
                C[(size_t)(grow + q) * N + gcol] = v;
                if (Cb) Cb[(size_t)(grow + q) * N + gcol] = f2bf(v);
            }
        }
    }
}

// unconditional (kernel 1)
__global__ __launch_bounds__(256)
void gemm_pipe2_128(const u16* __restrict__ Abf, const u16* __restrict__ Bbf,
                    const float* __restrict__ bias, float bias_scale,
                    float* __restrict__ C, u16* __restrict__ Cb, int M, int N, int K) {
    gemm_pipe2_body<128, 128, 4>(Abf, Bbf, bias, bias_scale, C, Cb, M, N, K);
}

// conditional: run only when spikes fired (flag != 0)
__global__ __launch_bounds__(256)
void gemm_pipe2_128_cond(const unsigned* __restrict__ flag,
                         const u16* __restrict__ Abf, const u16* __restrict__ Bbf,
                         const float* __restrict__ bias, float bias_scale,
                         float* __restrict__ C, u16* __restrict__ Cb, int M, int N, int K) {
    if (*flag == 0u) return;
    gemm_pipe2_body<128, 128, 4>(Abf, Bbf, bias, bias_scale, C, Cb, M, N, K);
}

__global__ __launch_bounds__(256, 2)
void gemm_pipe2_256_cond(const unsigned* __restrict__ flag,
                         const u16* __restrict__ Abf, const u16* __restrict__ Bbf,
                         const float* __restrict__ bias, float bias_scale,
                         float* __restrict__ C, u16* __restrict__ Cb, int M, int N, int K) {
    if (*flag == 0u) return;
    gemm_pipe2_body<128, 256, 4>(Abf, Bbf, bias, bias_scale, C, Cb, M, N, K);
}

// ---------------------------------------------------------------------------
// fp32 fallback kernels (tiny-workspace safety net)
// ---------------------------------------------------------------------------
__global__ void embed_kernel(const int* __restrict__ tok,
                             const float* __restrict__ table,
                             const float* __restrict__ mask,
                             float* __restrict__ emb) {
    int i = blockIdx.x * blockDim.x + threadIdx.x;
    const int n4 = NB * NE / 4;
    if (i >= n4) return;
    int b = i / (NE / 4);
    int c = i % (NE / 4);
    float4 t = ((const float4*)(table + (size_t)tok[b] * NE))[c];
    float4 m = ((const float4*)mask)[i];
    float4 o;
    o.x = t.x * m.x; o.y = t.y * m.y; o.z = t.z * m.z; o.w = t.w * m.w;
    ((float4*)emb)[i] = o;
}

__global__ void lif_kernel(const float* __restrict__ delta1,
                           const float* __restrict__ hidden,
                           const float* __restrict__ mask_lif,
                           const float* __restrict__ thr_p,
                           const float* __restrict__ leak_p,
                           float* __restrict__ hsum) {
    int i = blockIdx.x * blockDim.x + threadIdx.x;
    if (i >= NB * NH) return;
    const float thr = thr_p[0];
    const float leak = leak_p[0];
    float d = delta1[i];
    float m = hidden[i];
    float cnt = 0.0f;
#pragma unroll
    for (int t = 0; t < TSTEPS; ++t) {
        float mem = leak * m + d;
        float s = ((mem / thr - 1.0f) > 0.0f) ? 1.0f : 0.0f;
        m = mem - thr * s;
        cnt += s;
    }
    hsum[i] = cnt * mask_lif[i];
}

#define BM 128
#define BN 128
#define BK 16

__global__ __launch_bounds__(256)
void gemm_nt(const float* __restrict__ A, const float* __restrict__ Bm,
             const float* __restrict__ bias, float bias_scale,
             float* __restrict__ C, int M, int N, int K) {
    __shared__ float As[BK][BM + 4];
    __shared__ float Bs[BK][BN + 4];

    const int tid = threadIdx.x;
    const int bm = blockIdx.y * BM;
    const int bn = blockIdx.x * BN;
    const int tx = tid & 15;
    const int ty = tid >> 4;
    const int tm = ty * 8;
    const int tn0 = tx * 4;
    const int tn1 = 64 + tx * 4;

    float acc[8][8];
#pragma unroll
    for (int i = 0; i < 8; ++i)
#pragma unroll
        for (int j = 0; j < 8; ++j) acc[i][j] = 0.0f;

    constexpr int LDA4 = BK / 4;

    for (int k0 = 0; k0 < K; k0 += BK) {
#pragma unroll
        for (int idx = tid; idx < BM * LDA4; idx += 256) {
            int m = idx / LDA4, c = idx % LDA4;
            float4 v = *(const float4*)(A + (size_t)(bm + m) * K + k0 + c * 4);
            As[c * 4 + 0][m] = v.x;
            As[c * 4 + 1][m] = v.y;
            As[c * 4 + 2][m] = v.z;
            As[c * 4 + 3][m] = v.w;
        }
#pragma unroll
        for (int idx = tid; idx < BN * LDA4; idx += 256) {
            int n = idx / LDA4, c = idx % LDA4;
            float4 v = make_float4(0.f, 0.f, 0.f, 0.f);
            int gn = bn + n;
            if (gn < N) v = *(const float4*)(Bm + (size_t)gn * K + k0 + c * 4);
            Bs[c * 4 + 0][n] = v.x;
            Bs[c * 4 + 1][n] = v.y;
            Bs[c * 4 + 2][n] = v.z;
            Bs[c * 4 + 3][n] = v.w;
        }
        __syncthreads();

#pragma unroll
        for (int k = 0; k < BK; ++k) {
            float4 a0 = *(const float4*)&As[k][tm];
            float4 a1 = *(const float4*)&As[k][tm + 4];
            float4 b0 = *(const float4*)&Bs[k][tn0];
            float4 b1 = *(const float4*)&Bs[k][tn1];
            float a[8] = {a0.x, a0.y, a0.z, a0.w, a1.x, a1.y, a1.z, a1.w};
            float bb[8] = {b0.x, b0.y, b0.z, b0.w, b1.x, b1.y, b1.z, b1.w};
#pragma unroll
            for (int i = 0; i < 8; ++i)
#pragma unroll
                for (int j = 0; j < 8; ++j)
                    acc[i][j] = fmaf(a[i], bb[j], acc[i][j]);
        }
        __syncthreads();
    }

#pragma unroll
    for (int i = 0; i < 8; ++i) {
        size_t row = (size_t)(bm + tm + i) * N;
#pragma unroll
        for (int j = 0; j < 8; ++j) {
            int gn = bn + ((j < 4) ? (tn0 + j) : (tn1 + j - 4));
            if (gn < N)
                C[row + gn] = acc[i][j] + bias[gn] * bias_scale;
        }
    }
}

// ---------------------------------------------------------------------------
static inline int grid1d(int N, int TBN) {
    int P = (N + TBN - 1) / TBN;
    int P8 = ((P + 7) / 8) * 8;
    return 8 * P8;                  // 8 row-blocks x padded panels
}

extern "C" void kernel_launch(void* const* d_in, const int* in_sizes, int n_in,
                              void* d_out, int out_size, void* d_ws, size_t ws_size,
                              hipStream_t stream) {
    const int*   tok      = (const int*)  d_in[0];
    const float* hidden   = (const float*)d_in[1];
    const float* table    = (const float*)d_in[2];
    const float* W1       = (const float*)d_in[3];
    const float* b1       = (const float*)d_in[4];
    const float* W2       = (const float*)d_in[5];
    const float* b2       = (const float*)d_in[6];
    const float* fc_W     = (const float*)d_in[7];
    const float* fc_b     = (const float*)d_in[8];
    const float* thr      = (const float*)d_in[9];
    const float* leak     = (const float*)d_in[10];
    const float* mask_emb = (const float*)d_in[11];
    const float* mask_lif = (const float*)d_in[12];

    float* linear = (float*)d_out;                   // [B,V]
    float* outbuf = (float*)d_out + (size_t)NB * NV; // [B,H]

    const size_t SZ_FLAG = 16;                   // two flags live here
    const size_t SZ_Y   = ((size_t)NV * 4 + 15) / 16 * 16;  // y[V]
    const size_t SZ_EB  = (size_t)NB * NE * 2;   // ebf
    const size_t SZ_D1  = (size_t)NB * NH * 4;   // delta1 fp32
    const size_t SZ_HB  = (size_t)NB * NH * 2;   // hbf
    const size_t SZ_OB  = (size_t)NB * NH * 2;   // obf
    const size_t SZ_W1B = (size_t)NH * NE * 2;   // W1 bf16
    const size_t SZ_W2B = (size_t)NH * NH * 2;   // W2 bf16
    const size_t SZ_WB  = (size_t)NV * NH * 2;   // fc_W bf16 (~103 MB)
    const size_t need_bf = SZ_FLAG + SZ_Y + SZ_EB + SZ_D1 + SZ_HB + SZ_OB
                         + SZ_W1B + SZ_W2B + SZ_WB;

    char* p = (char*)d_ws;

    if (ws_size >= need_bf) {
        unsigned* flag    = (unsigned*)p;            // [0] spike, [1] b2-nonzero
        unsigned* flag_b2 = (unsigned*)p + 1;
        p += SZ_FLAG;
        float* y      = (float*)p;     p += SZ_Y;
        u16*   ebf    = (u16*)p;       p += SZ_EB;
        float* delta1 = (float*)p;     p += SZ_D1;
        u16*   hbf    = (u16*)p;       p += SZ_HB;
        u16*   obf    = (u16*)p;       p += SZ_OB;
        u16*   w1b    = (u16*)p;       p += SZ_W1B;
        u16*   w2b    = (u16*)p;       p += SZ_W2B;
        u16*   fcwb   = (u16*)p;       p += SZ_WB;

        // flags (spike=0, b2-nonzero detect)
        init_kernel<<<1, 256, 0, stream>>>(b2, flag, flag_b2);
        // W1 convert + embedding (merged, 1024 blocks)
        prep_kernel<<<1024, 256, 0, stream>>>(W1, w1b, tok, table, mask_emb, ebf);
        // 1: delta1 = ebf @ w1b^T + b1   (M=B, N=H, K=E) — always
        gemm_pipe2_128<<<grid1d(NH, 128), 256, 0, stream>>>(ebf, w1b, b1, 1.0f,
                                                            delta1, (u16*)nullptr, NB, NH, NE);
        // 2: LIF -> hbf (bf16) + spike flag
        {
            int n = NB * NH / 4;
            lif_bf16_flag_kernel<<<(n + 255) / 256, 256, 0, stream>>>(delta1, hidden, mask_lif,
                                                                      thr, leak, hbf, flag);
        }
        // ---- zero-spike fast path (flag == 0) ----
        bcast_out_kernel<<<512, 256, 0, stream>>>(flag, b2, outbuf);
        matvec_fc_kernel<<<2048, 256, 0, stream>>>(flag, flag_b2, b2, fc_W, fc_b, y);
        {
            dim3 grid((NV + 1023) / 1024, NB / 8);
            bcast_linear_kernel<<<grid, 256, 0, stream>>>(flag, flag_b2, y, fc_b, linear);
        }
        // ---- spike path (flag != 0): full MFMA decode ----
        cvt_cond_kernel<<<2560, 256, 0, stream>>>(flag, W2, w2b, fc_W, fcwb);
        gemm_pipe2_128_cond<<<grid1d(NH, 128), 256, 0, stream>>>(flag, hbf, w2b, b2, (float)TSTEPS,
                                                                 outbuf, obf, NB, NH, NH);
        gemm_pipe2_256_cond<<<grid1d(NV, 256), 256, 0, stream>>>(flag, obf, fcwb, fc_b, 1.0f,
                                                                 linear, (u16*)nullptr, NB, NV, NH);
    } else {
        // ----- pure fp32 fallback -----
        float* emb    = (float*)p;  p += (size_t)NB * NE * 4;
        float* delta1 = (float*)p;  p += SZ_D1;
        float* hsum   = (float*)p;

        int n4 = NB * NE / 4;
        embed_kernel<<<(n4 + 255) / 256, 256, 0, stream>>>(tok, table, mask_emb, emb);
        {
            dim3 grid(NH / BN, NB / BM);
            gemm_nt<<<grid, 256, 0, stream>>>(emb, W1, b1, 1.0f, delta1, NB, NH, NE);
        }
        {
            int n = NB * NH;
            lif_kernel<<<(n + 255) / 256, 256, 0, stream>>>(delta1, hidden, mask_lif,
                                                            thr, leak, hsum);
        }
        {
            dim3 grid(NH / BN, NB / BM);
            gemm_nt<<<grid, 256, 0, stream>>>(hsum, W2, b2, (float)TSTEPS, outbuf, NB, NH, NH);
        }
        {
            dim3 grid((NV + BN - 1) / BN, NB / BM);
            gemm_nt<<<grid, 256, 0, stream>>>(outbuf, fc_W, fc_b, 1.0f, linear, NB, NV, NH);
        }
    }
}